// Round 14
// baseline (137.256 us; speedup 1.0000x reference)
//
#include <hip/hip_runtime.h>
#include <math.h>

namespace {
constexpr int Ln = 2048;
constexpr int Dn = 1024;
constexpr int Mn = 4096;   // B*L
constexpr float QSCALE = 0.25f * 1.44269504088896340736f; // 2/sqrt(64) * log2(e)
}

typedef unsigned short u16;
typedef unsigned int u32;
typedef __attribute__((ext_vector_type(4))) float f32x4;
typedef __attribute__((ext_vector_type(8))) __bf16 bf16x8;
typedef __attribute__((ext_vector_type(4))) unsigned short u16x4;
typedef __attribute__((ext_vector_type(8))) unsigned short u16x8;
typedef __attribute__((ext_vector_type(4))) unsigned int u32x4;

// ============================================================================
// LAYOUT CONVENTIONS (write-side must match read-side):
// * bf16 matrices are stored in global PRE-SWIZZLED: within each 64-element
//   (128B) k-slice of a row l, the 16B block b sits at position b ^ (l&7).
//   A fragment reader (lane c,g; k-half kk) reads the 16B at position
//   (kk*4+g) ^ (c&7); fragment rows ≡ c (mod 8) so this yields block kk*4+g.
// * Q/K projections store head features in SLOT order s = 4*(d&15) + (d>>4).
//   Q and K share the permutation => dot products unchanged.  V stored same
//   way; transpose_v un-permutes.  cat uses the same slot order per head,
//   compensated by permuting W_O's input columns.
// * v_T ([bh][d][2048]) position y within each 64-chunk holds physical key
//   nu(y) = (y>>5)*32 + ((y>>2)&1)*16 + ((y>>3)&3)*4 + (y&3), so the PV
//   A-fragment equals exp2(sf[..]) of the SAME lane after swapped QK^T.
// * Fixed-max softmax (hyperboloid: scores<=0) => split-KV partials combine
//   by pure addition; Lorentz normalize is scale-invariant => no denominator.
// * gemm_qkv AND attn_mfma are BARRIER-FREE and LDS-FREE: fragments loaded
//   per-lane directly from swizzled global.  gemm_qkv's k-loop is fully
//   unrolled so all load offsets are 13-bit immediates (zero address VALU).
//   attn uses 64 q-rows/wave to halve per-FLOP K/V fragment traffic.
// ============================================================================

__device__ __forceinline__ u16 f2bf(float f) {
    union { float f; unsigned u; } cv; cv.f = f;
    unsigned u = cv.u + 0x7fffu + ((cv.u >> 16) & 1u);
    return (u16)(u >> 16);
}
__device__ __forceinline__ float bf2f(u16 h) {
    union { unsigned u; float f; } cv; cv.u = ((unsigned)h) << 16;
    return cv.f;
}

__device__ __forceinline__ u32 pkbf(float a, float b) {
    union { __bf16 h[2]; u32 u; } cv;
    cv.h[0] = (__bf16)a; cv.h[1] = (__bf16)b;
    return cv.u;
}

// native exp2: inputs here are in [-50, 0.5] -> normal results.
#if __has_builtin(__builtin_amdgcn_exp2f)
__device__ __forceinline__ float exp2_fast(float x) {
    return __builtin_amdgcn_exp2f(x);
}
#else
__device__ __forceinline__ float exp2_fast(float x) {
    float r;
    asm("v_exp_f32 %0, %1" : "=v"(r) : "v"(x));
    return r;
}
#endif

// DPP cross-lane (16-lane row) sum — VALU pipe, no LDS
template <int CTRL>
__device__ __forceinline__ float dppf(float x) {
    return __int_as_float(__builtin_amdgcn_update_dpp(
        0, __float_as_int(x), CTRL, 0xf, 0xf, true));
}
__device__ __forceinline__ float red16_add(float x) {
    x += dppf<0xB1>(x);    // quad_perm(1,0,3,2)
    x += dppf<0x4E>(x);    // quad_perm(2,3,0,1)
    x += dppf<0x141>(x);   // row_half_mirror
    x += dppf<0x140>(x);   // row_mirror
    return x;
}

__device__ __forceinline__ void gload16(const void* g, void* l) {
    __builtin_amdgcn_global_load_lds(
        (const __attribute__((address_space(1))) unsigned int*)g,
        (__attribute__((address_space(3))) unsigned int*)l, 16, 0, 0);
}

// ---------------------------------------------------------------------------
// f32 -> bf16 convert of the 3 inputs, swizzled global layout (rows of 1024).
// ---------------------------------------------------------------------------
__global__ __launch_bounds__(256)
void cvt_in3(const float* __restrict__ i0, const float* __restrict__ i1,
             const float* __restrict__ i2,
             u16* __restrict__ o0, u16* __restrict__ o1, u16* __restrict__ o2)
{
    const int z = blockIdx.y;
    const float* in = z == 0 ? i0 : (z == 1 ? i1 : i2);
    u16* out       = z == 0 ? o0 : (z == 1 ? o1 : o2);
    int i = blockIdx.x * 256 + threadIdx.x;        // group of 4 elements
    f32x4 v = ((const f32x4*)in)[i];
    u16x4 o;
#pragma unroll
    for (int j = 0; j < 4; ++j) o[j] = f2bf(v[j]);
    int l = i >> 8;                // row
    int e = (i & 255) * 4;         // element within row
    int idx = l * 1024 + (e & ~63) + (((((e >> 3) & 7) ^ (l & 7))) << 3) + (e & 7);
    *(u16x4*)&out[idx] = o;
}

// ---------------------------------------------------------------------------
// Weights cvt: wq/wk/wv plain swizzle; wo (z==3) also permutes input columns
// to cat's per-head slot order.
// ---------------------------------------------------------------------------
__global__ __launch_bounds__(256)
void cvt_w(const float* __restrict__ w0, const float* __restrict__ w1,
           const float* __restrict__ w2, const float* __restrict__ w3,
           u16* __restrict__ q0, u16* __restrict__ q1,
           u16* __restrict__ q2, u16* __restrict__ q3)
{
    const int z = blockIdx.y;
    int i = blockIdx.x * 256 + threadIdx.x;
    if (z < 3) {
        const float* in = z == 0 ? w0 : (z == 1 ? w1 : w2);
        u16* out       = z == 0 ? q0 : (z == 1 ? q1 : q2);
        f32x4 v = ((const f32x4*)in)[i];
        u16x4 o;
#pragma unroll
        for (int j = 0; j < 4; ++j) o[j] = f2bf(v[j]);
        int l = i >> 8;
        int e = (i & 255) * 4;
        int idx = l * 1024 + (e & ~63) + (((((e >> 3) & 7) ^ (l & 7))) << 3) + (e & 7);
        *(u16x4*)&out[idx] = o;
    } else {
        int o  = i >> 8;             // output row of W_O (natural)
        int s0 = (i & 255) * 4;      // out column-slot base
        int h = s0 >> 6, sl = s0 & 63, a = sl >> 2;
        const float* src = w3 + (size_t)o * 1024 + h * 64;
        // slot s0+j holds input feature h*64 + j*16 + a
        u16x4 ov = { f2bf(src[a]), f2bf(src[16 + a]),
                     f2bf(src[32 + a]), f2bf(src[48 + a]) };
        int idx = o * 1024 + h * 64 + (((sl >> 3) ^ (o & 7)) << 3) + (sl & 7);
        *(u16x4*)&q3[idx] = ov;
    }
}

// ---------------------------------------------------------------------------
// Q/K/V projection GEMM + fused per-head Lorentz projection.
// 128x128 tile, 4 waves (64x64/wave, acc 4x4).  BARRIER-FREE, LDS-FREE:
// per-lane fragment loads from swizzled global, register-dbuf one kk-step
// ahead; k-loop FULLY UNROLLED so every load offset is an immediate.
// 768 blocks (id: m=id&31 [XCD=m&7], n=(id>>5)&7, z=id>>8) -> 3 blocks/CU.
// Output bf16 [b][h][l][64slots], slot-permuted + byte-swizzled.
// ---------------------------------------------------------------------------
__global__ __launch_bounds__(256)
void gemm_qkv(const u16* __restrict__ xq, const u16* __restrict__ xk,
              const u16* __restrict__ xv, const u16* __restrict__ wq,
              const u16* __restrict__ wk, const u16* __restrict__ wv,
              const float* __restrict__ bq, const float* __restrict__ bk,
              const float* __restrict__ bv,
              u16* __restrict__ oq, u16* __restrict__ ok, u16* __restrict__ ov)
{
    const int t = threadIdx.x;
    const int lane = t & 63, w = t >> 6;
    const int g = lane >> 4, c = lane & 15;
    const int wr = w >> 1, wc = w & 1;
    const int id = blockIdx.x;
    const int bm = (id & 31) * 128;
    const int bn = ((id >> 5) & 7) * 128;
    const int z  = id >> 8;

    const u16* A = z == 0 ? xq : (z == 1 ? xk : xv);
    const u16* W = z == 0 ? wq : (z == 1 ? wk : wv);
    const float* bias = z == 0 ? bq : (z == 1 ? bk : bv);
    u16* Ct = z == 0 ? oq : (z == 1 ? ok : ov);
    const float scale = z == 0 ? QSCALE : 1.f;
    const float tsign = z == 0 ? -1.f : 1.f;

    // per-lane fragment bases (rows ≡ c mod 8 -> swizzle XOR uses c&7)
    const int s7 = c & 7;
    const int ko0 = ((0 + g) ^ s7) << 3;     // kk=0 elem offset in 64-slice
    const int ko1 = ((4 + g) ^ s7) << 3;     // kk=1
    const u16* Ab[4];
    const u16* Bb[4];
#pragma unroll
    for (int mi = 0; mi < 4; ++mi)
        Ab[mi] = A + (size_t)(bm + wr * 64 + mi * 16 + c) * Dn;
#pragma unroll
    for (int ni = 0; ni < 4; ++ni)
        Bb[ni] = W + (size_t)(bn + wc * 64 + ni * 16 + c) * Dn;

    f32x4 acc[4][4];
    const f32x4 z4 = {0.f, 0.f, 0.f, 0.f};
#pragma unroll
    for (int i = 0; i < 4; ++i)
#pragma unroll
        for (int j = 0; j < 4; ++j) acc[i][j] = z4;

    bf16x8 a0[4], b0[4], a1[4], b1[4];
#pragma unroll
    for (int mi = 0; mi < 4; ++mi) a0[mi] = *(const bf16x8*)(Ab[mi] + ko0);
#pragma unroll
    for (int ni = 0; ni < 4; ++ni) b0[ni] = *(const bf16x8*)(Bb[ni] + ko0);

#pragma unroll
    for (int ki = 0; ki < 16; ++ki) {
        const int kb = ki * 64;
        // prefetch kk=1 of this k-tile (immediate offsets after unroll)
#pragma unroll
        for (int mi = 0; mi < 4; ++mi) a1[mi] = *(const bf16x8*)(Ab[mi] + kb + ko1);
#pragma unroll
        for (int ni = 0; ni < 4; ++ni) b1[ni] = *(const bf16x8*)(Bb[ni] + kb + ko1);
        __builtin_amdgcn_s_setprio(1);
#pragma unroll
        for (int mi = 0; mi < 4; ++mi)
#pragma unroll
            for (int ni = 0; ni < 4; ++ni)
                acc[mi][ni] = __builtin_amdgcn_mfma_f32_16x16x32_bf16(
                    a0[mi], b0[ni], acc[mi][ni], 0, 0, 0);
        __builtin_amdgcn_s_setprio(0);
        if (ki + 1 < 16) {   // prefetch kk=0 of next k-tile
#pragma unroll
            for (int mi = 0; mi < 4; ++mi)
                a0[mi] = *(const bf16x8*)(Ab[mi] + kb + 64 + ko0);
#pragma unroll
            for (int ni = 0; ni < 4; ++ni)
                b0[ni] = *(const bf16x8*)(Bb[ni] + kb + 64 + ko0);
        }
        __builtin_amdgcn_s_setprio(1);
#pragma unroll
        for (int mi = 0; mi < 4; ++mi)
#pragma unroll
            for (int ni = 0; ni < 4; ++ni)
                acc[mi][ni] = __builtin_amdgcn_mfma_f32_16x16x32_bf16(
                    a1[mi], b1[ni], acc[mi][ni], 0, 0, 0);
        __builtin_amdgcn_s_setprio(0);
    }

    // fused per-head Lorentz projection epilogue (verified in r12)
    const int hcb = bn + wc * 64;
    const int h = hcb >> 6;
#pragma unroll
    for (int mi = 0; mi < 4; ++mi)
#pragma unroll
        for (int j = 0; j < 4; ++j) {
            int ll = bm + wr * 64 + mi * 16 + g * 4 + j;
            float zv[4];
#pragma unroll
            for (int ni = 0; ni < 4; ++ni)
                zv[ni] = acc[mi][ni][j] + bias[hcb + ni * 16 + c];
            float loc = zv[0]*zv[0] + zv[1]*zv[1] + zv[2]*zv[2] + zv[3]*zv[3];
            if (c == 0) loc -= zv[0] * zv[0];     // z0 is DISCARDED (once!)
            loc = red16_add(loc);                 // = sum of space^2
            float tval = sqrtf(1.f + loc);
            float v0 = (c == 0) ? tsign * tval : zv[0];
            int bb = ll >> 11, l2 = ll & 2047;
            u16* dst = Ct + (((size_t)bb * 16 + h) * Ln + l2) * 64;
            u16x4 pkv = { f2bf(v0 * scale), f2bf(zv[1] * scale),
                          f2bf(zv[2] * scale), f2bf(zv[3] * scale) };
            *(u16x4*)&dst[(4 * c) ^ ((ll & 7) << 3)] = pkv;
        }
}

// ---------------------------------------------------------------------------
// V transpose: [bh][l][64 slots,swz] -> v_T [bh][d][2048] where position y
// within each 64-chunk holds key nu(y) (see header), byte-swizzled per (d&7).
// ---------------------------------------------------------------------------
__global__ __launch_bounds__(256)
void transpose_v(const u16* __restrict__ vin, u16* __restrict__ vout)
{
    __shared__ u16 raw[64 * 64];     // straight copy of the swizzled tile
    const int t = threadIdx.x;
    const int bh = blockIdx.x, lc = blockIdx.y;
    const u16* src = vin + ((size_t)bh * Ln + lc * 64) * 64;
#pragma unroll
    for (int p = 0; p < 2; ++p) {
        int ci = p * 256 + t;
        *(u16x8*)&raw[ci * 8] = *(const u16x8*)(src + ci * 8);
    }
    __syncthreads();
    const int d = t >> 2, cp0 = (t & 3) * 16;
    const int s = ((d & 15) << 2) | (d >> 4);   // slot of true feature d
    u16 buf[16];
#pragma unroll
    for (int i = 0; i < 16; ++i) {
        int cp = cp0 + i;
        // physical key for v_T position cp:
        int n = ((cp >> 5) << 5) | (((cp >> 2) & 1) << 4) | (((cp >> 3) & 3) << 2) | (cp & 3);
        buf[i] = raw[n * 64 + ((((s >> 3) ^ (n & 7)) << 3) | (s & 7))];
    }
    u16* dst = vout + ((size_t)bh * 64 + d) * Ln + lc * 64;
    int b0 = cp0 >> 3;
    *(u16x8*)&dst[((b0 ^ (d & 7)) << 3)]       = *(const u16x8*)&buf[0];
    *(u16x8*)&dst[(((b0 + 1) ^ (d & 7)) << 3)] = *(const u16x8*)&buf[8];
}

// ---------------------------------------------------------------------------
// Split-KV MFMA flash attention, BARRIER-FREE / LDS-FREE.  512 blocks
// (id: XCD grp = id&7, qb = (id>>3)&7, gidx = (id&7)|((id>>6)<<3)):
// block = 256 q-rows x 1024 keys; 4 waves x 64 q-rows/wave.  K/V fragments
// loaded per-lane directly from swizzled global (shared K/V chunk -> L1
// hits across waves).  Swapped QK^T, in-register P, fixed-max softmax,
// no denominator.  Writes bf16 PARTIAL O; halves add in attn_combine.
// ---------------------------------------------------------------------------
__global__ __launch_bounds__(256)
void attn_mfma(const u16* __restrict__ qt, const u16* __restrict__ kt,
               const u16* __restrict__ vT, u16* __restrict__ part)
{
    const int t = threadIdx.x;
    const int lane = t & 63, w = t >> 6;
    const int g = lane >> 4, c = lane & 15;
    const int id  = blockIdx.x;
    const int qb  = (id >> 3) & 7;
    const int gidx = (id & 7) | ((id >> 6) << 3);   // 0..63
    const int bh  = gidx & 31;
    const int kvh = gidx >> 5;
    const int q0  = qb * 256;
    const u16* Q = qt + (size_t)bh * Ln * 64;
    const u16* K = kt + (size_t)bh * Ln * 64 + (size_t)kvh * (1024 * 64);
    const u16* V = vT + (size_t)bh * 64 * (size_t)Ln + kvh * 1024;

    const int s7 = c & 7;
    const int ko0 = ((0 + g) ^ s7) << 3;
    const int ko1 = ((4 + g) ^ s7) << 3;

    // Q fragments (4 row-frags x 2 k-halves) in registers for the whole sweep
    bf16x8 qa[4][2];
#pragma unroll
    for (int mi = 0; mi < 4; ++mi) {
        int row = q0 + w * 64 + mi * 16 + c;
        qa[mi][0] = *(const bf16x8*)(Q + (size_t)row * 64 + ko0);
        qa[mi][1] = *(const bf16x8*)(Q + (size_t)row * 64 + ko1);
    }

    // K row-bases (rows ni*16+c) and V row-bases (rows di*16+c)
    const u16* KB[4];
    const u16* VB[4];
#pragma unroll
    for (int ni = 0; ni < 4; ++ni) KB[ni] = K + (size_t)(ni * 16 + c) * 64;
#pragma unroll
    for (int di = 0; di < 4; ++di) VB[di] = V + (size_t)(di * 16 + c) * Ln;

    f32x4 o[4][4];
    const f32x4 z4 = {0.f, 0.f, 0.f, 0.f};
#pragma unroll
    for (int mi = 0; mi < 4; ++mi)
#pragma unroll
        for (int di = 0; di < 4; ++di) o[mi][di] = z4;

    for (int ch = 0; ch < 16; ++ch) {
        const int kof = ch * 4096;   // 64 rows * 64 elems per chunk
        const int vof = ch * 64;     // 64 positions per chunk

        // ---- QK^T swapped: sf[mi][ni][j] = S[k=16ni+4g+j][q=16mi+c] ----
        f32x4 sf[4][4];
#pragma unroll
        for (int mi = 0; mi < 4; ++mi)
#pragma unroll
            for (int ni = 0; ni < 4; ++ni) sf[mi][ni] = z4;
#pragma unroll
        for (int kk = 0; kk < 2; ++kk) {
            const int ko = kk ? ko1 : ko0;
            bf16x8 kb[4];
#pragma unroll
            for (int ni = 0; ni < 4; ++ni)
                kb[ni] = *(const bf16x8*)(KB[ni] + kof + ko);
            __builtin_amdgcn_s_setprio(1);
#pragma unroll
            for (int mi = 0; mi < 4; ++mi)
#pragma unroll
                for (int ni = 0; ni < 4; ++ni)
                    sf[mi][ni] = __builtin_amdgcn_mfma_f32_16x16x32_bf16(
                        kb[ni], qa[mi][kk], sf[mi][ni], 0, 0, 0);
            __builtin_amdgcn_s_setprio(0);
        }

        // ---- softmax numerator (fixed max 0) + P frags in registers ----
        bf16x8 paf[4][2];
#pragma unroll
        for (int mi = 0; mi < 4; ++mi) {
            float ex[4][4];
#pragma unroll
            for (int ni = 0; ni < 4; ++ni)
#pragma unroll
                for (int j = 0; j < 4; ++j)
                    ex[ni][j] = exp2_fast(sf[mi][ni][j]);
            u32x4 p0 = { pkbf(ex[0][0], ex[0][1]), pkbf(ex[0][2], ex[0][3]),
                         pkbf(ex[1][0], ex[1][1]), pkbf(ex[1][2], ex[1][3]) };
            u32x4 p1 = { pkbf(ex[2][0], ex[2][1]), pkbf(ex[2][2], ex[2][3]),
                         pkbf(ex[3][0], ex[3][1]), pkbf(ex[3][2], ex[3][3]) };
            paf[mi][0] = __builtin_bit_cast(bf16x8, p0);
            paf[mi][1] = __builtin_bit_cast(bf16x8, p1);
        }

        // ---- PV (32 MFMA): O[q][d] += P[q][k] V[k][d] ----
#pragma unroll
        for (int kk = 0; kk < 2; ++kk) {
            const int ko = kk ? ko1 : ko0;
            bf16x8 vb[4];
#pragma unroll
            for (int di = 0; di < 4; ++di)
                vb[di] = *(const bf16x8*)(VB[di] + vof + ko);
            __builtin_amdgcn_s_setprio(1);
#pragma unroll
            for (int di = 0; di < 4; ++di)
#pragma unroll
                for (int mi = 0; mi < 4; ++mi)
                    o[mi][di] = __builtin_amdgcn_mfma_f32_16x16x32_bf16(
                        paf[mi][kk], vb[di], o[mi][di], 0, 0, 0);
            __builtin_amdgcn_s_setprio(0);
        }
    }

    // ---- epilogue: store bf16 partial O ----
    u16* P = part + (size_t)(kvh * 32 + bh) * (4 * 2048 * 16);
#pragma unroll
    for (int mi = 0; mi < 4; ++mi)
#pragma unroll
        for (int j = 0; j < 4; ++j) {
            int row = q0 + w * 64 + mi * 16 + g * 4 + j;
#pragma unroll
            for (int di = 0; di < 4; ++di)
                P[(di * 2048 + row) * 16 + c] = f2bf(o[mi][di][j]);
        }
}

// ---------------------------------------------------------------------------
// Combine the two KV-half partials, Lorentz-normalize per head row, write
// bf16 cat (slot order + swizzle).  16-lane group per (bh,q) row.
// ---------------------------------------------------------------------------
__global__ __launch_bounds__(256)
void attn_combine(const u16* __restrict__ part, u16* __restrict__ cat)
{
    const int grp = blockIdx.x * 16 + (threadIdx.x >> 4);  // row id in [0,65536)
    const int c = threadIdx.x & 15;
    const int bh = grp >> 11, q = grp & 2047;
    const u16* P0 = part + (size_t)bh * (4 * 2048 * 16);
    const u16* P1 = part + (size_t)(32 + bh) * (4 * 2048 * 16);
    float mu[4];
#pragma unroll
    for (int di = 0; di < 4; ++di) {
        int idx = (di * 2048 + q) * 16 + c;
        mu[di] = bf2f(P0[idx]) + bf2f(P1[idx]);
    }
    float loc = mu[0]*mu[0] + mu[1]*mu[1] + mu[2]*mu[2] + mu[3]*mu[3];
    if (c == 0) loc -= 2.f * mu[0] * mu[0];   // Lorentz inner <o,o>
    loc = red16_add(loc);
    float rn = rsqrtf(fmaxf(fabsf(loc), 1e-6f));
    const int b = bh >> 4, h = bh & 15;
    u16* dst = cat + ((size_t)b * Ln + q) * Dn + h * 64;
    u16x4 pkv = { f2bf(mu[0] * rn), f2bf(mu[1] * rn),
                  f2bf(mu[2] * rn), f2bf(mu[3] * rn) };
    *(u16x4*)&dst[(4 * c) ^ ((q & 7) << 3)] = pkv;
}

// ---------------------------------------------------------------------------
// Output GEMM: out[4096][1024] = cat @ wo^T + b_O (f32 out).
// 64x128 tile, BK=64, double-buffered (48 KB), XCD-swizzled 512 blocks.
// (round-10 proven structure)
// ---------------------------------------------------------------------------
__global__ __launch_bounds__(256)
void gemm_o(const u16* __restrict__ A, const u16* __restrict__ B,
            const float* __restrict__ bias, float* __restrict__ C)
{
    __shared__ u16 As[2][64 * 64];
    __shared__ u16 Bs[2][128 * 64];
    const int t = threadIdx.x;
    const int lane = t & 63, w = t >> 6;
    const int g = lane >> 4, c = lane & 15;
    const int wr = w >> 1, wc = w & 1;
    // XCD decode: y = (id&7)*8 + ((id>>3)&7) in [0,64), x = id>>6 in [0,8)
    const int id = blockIdx.x;
    const int bm = ((id & 7) * 8 + ((id >> 3) & 7)) * 64;
    const int bn = (id >> 6) * 128;

    f32x4 acc[2][4];
    const f32x4 z4 = {0.f, 0.f, 0.f, 0.f};
#pragma unroll
    for (int i = 0; i < 2; ++i)
#pragma unroll
        for (int j = 0; j < 4; ++j) acc[i][j] = z4;

    const int sr = t >> 3, sb2 = (t & 7) * 8;
    const u16* Ap = A + (size_t)(bm + sr) * Dn + sb2;
    const u16* Bp = B + (size_t)(bn + sr) * Dn + sb2;

    auto stage = [&](int buf, int k0) {
        gload16(Ap + k0,            &As[buf][t * 8]);
        gload16(Ap + 32 * Dn + k0,  &As[buf][(256 + t) * 8]);
        gload16(Bp + k0,            &Bs[buf][t * 8]);
        gload16(Bp + 32 * Dn + k0,  &Bs[buf][(256 + t) * 8]);
        gload16(Bp + 64 * Dn + k0,  &Bs[buf][(512 + t) * 8]);
        gload16(Bp + 96 * Dn + k0,  &Bs[buf][(768 + t) * 8]);
    };

    stage(0, 0);
    for (int ki = 0; ki < 16; ++ki) {
        __syncthreads();
        if (ki + 1 < 16) stage((ki + 1) & 1, (ki + 1) * 64);
        const u16* as = As[ki & 1];
        const u16* bs = Bs[ki & 1];
#pragma unroll
        for (int kk = 0; kk < 2; ++kk) {
            const int so = ((kk * 4 + g) ^ (c & 7)) << 3;
            bf16x8 a[2], b[4];
#pragma unroll
            for (int mi = 0; mi < 2; ++mi)
                a[mi] = *(const bf16x8*)&as[(wr * 32 + mi * 16 + c) * 64 + so];
#pragma unroll
            for (int ni = 0; ni < 4; ++ni)
                b[ni] = *(const bf16x8*)&bs[(wc * 64 + ni * 16 + c) * 64 + so];
            __builtin_amdgcn_s_setprio(1);
#pragma unroll
            for (int mi = 0; mi < 2; ++mi)
#pragma unroll
                for (int ni = 0; ni < 4; ++ni)
                    acc[mi][ni] = __builtin_amdgcn_mfma_f32_16x16x32_bf16(
                        a[mi], b[ni], acc[mi][ni], 0, 0, 0);
            __builtin_amdgcn_s_setprio(0);
        }
    }

#pragma unroll
    for (int mi = 0; mi < 2; ++mi)
#pragma unroll
        for (int j = 0; j < 4; ++j) {
            size_t row = bm + wr * 32 + mi * 16 + g * 4 + j;
#pragma unroll
            for (int ni = 0; ni < 4; ++ni) {
                int col = bn + wc * 64 + ni * 16 + c;
                C[row * Dn + col] = acc[mi][ni][j] + bias[col];
            }
        }
}

// ---------------------------------------------------------------------------
// Full-row (D=1024) Lorentz projection on f32 output rows.
// ---------------------------------------------------------------------------
__global__ __launch_bounds__(256)
void lorentz_row_full(float* __restrict__ z)
{
    __shared__ float red[4];
    const int t = threadIdx.x;
    const size_t base = (size_t)blockIdx.x * Dn;
    float4 v = *(const float4*)&z[base + t * 4];
    if (t == 0) v.x = 0.f;
    float ssq = v.x * v.x + v.y * v.y + v.z * v.z + v.w * v.w;
#pragma unroll
    for (int off = 32; off; off >>= 1) ssq += __shfl_xor(ssq, off);
    if ((t & 63) == 0) red[t >> 6] = ssq;
    __syncthreads();
    if (t == 0) z[base] = sqrtf(1.0f + red[0] + red[1] + red[2] + red[3]);
}

// ---------------------------------------------------------------------------
extern "C" void kernel_launch(void* const* d_in, const int* in_sizes, int n_in,
                              void* d_out, int out_size, void* d_ws, size_t ws_size,
                              hipStream_t stream)
{
    const float* query = (const float*)d_in[0];
    const float* key_  = (const float*)d_in[1];
    const float* value = (const float*)d_in[2];
    const float* W_Q   = (const float*)d_in[3];
    const float* b_Q   = (const float*)d_in[4];
    const float* W_K   = (const float*)d_in[5];
    const float* b_K   = (const float*)d_in[6];
    const float* W_V   = (const float*)d_in[7];
    const float* b_V   = (const float*)d_in[8];
    const float* W_O   = (const float*)d_in[9];
    const float* b_O   = (const float*)d_in[10];

    // ws layout (u16 elems; 64 MiB budget).  part aliases wq/wk/wv/v_ln,
    // all of which are dead before attn_mfma runs.
    const size_t MD = (size_t)Mn * Dn;   // 4M elems (8 MiB)
    const size_t DD = (size_t)Dn * Dn;   // 1M elems (2 MiB)
    u16* xq   = (u16*)d_ws;              //  0M..4M   swz input q
    u16* xk   = xq + MD;                 //  4M..8M   swz input k
    u16* xv   = xk + MD;                 //  8M..12M  swz input v
    u16* wo   = xv + MD;                 // 12M..13M  W_O (swz + col perm)
    u16* q_t  = wo + DD;                 // 13M..17M  [b][h][l][64slots]
    u16* k_t  = q_t + MD;                // 17M..21M
    u16* wq   = k_t + MD;                // 21M..22M
    u16* wk   = wq + DD;                 // 22M..23M
    u16* wv   = wk + DD;                 // 23M..24M
    u16* v_ln = wv + DD;                 // 24M..28M  V projection
    u16* part = wq;                      // 21M..29M  bf16 partials (16 MiB)
    u16* v_T  = xv;                      // alias: xv dead after gemm_qkv
    u16* cat  = xk;                      // alias: xk dead after gemm_qkv

    dim3 ci(Mn * Dn / 1024, 3);                // (4096, 3)
    cvt_in3<<<ci, 256, 0, stream>>>(query, key_, value, xq, xk, xv);
    dim3 cw(Dn * Dn / 1024, 4);                // (1024, 4)
    cvt_w<<<cw, 256, 0, stream>>>(W_Q, W_K, W_V, W_O, wq, wk, wv, wo);

    gemm_qkv<<<768, 256, 0, stream>>>(xq, xk, xv, wq, wk, wv,
                                      b_Q, b_K, b_V, q_t, k_t, v_ln);

    dim3 tg(32, Ln / 64);                      // (32, 32)
    transpose_v<<<tg, 256, 0, stream>>>(v_ln, v_T);

    attn_mfma<<<512, 256, 0, stream>>>(q_t, k_t, v_T, part);  // XCD-swizzled 1D

    attn_combine<<<4096, 256, 0, stream>>>(part, cat);

    gemm_o<<<512, 256, 0, stream>>>(cat, wo, b_O, (float*)d_out);
    lorentz_row_full<<<Mn, 256, 0, stream>>>((float*)d_out);
}

// Round 15
// 137.109 us; speedup vs baseline: 1.0011x; 1.0011x over previous
//
#include <hip/hip_runtime.h>
#include <math.h>

namespace {
constexpr int Ln = 2048;
constexpr int Dn = 1024;
constexpr int Mn = 4096;   // B*L
constexpr float QSCALE = 0.25f * 1.44269504088896340736f; // 2/sqrt(64) * log2(e)
}

typedef unsigned short u16;
typedef unsigned int u32;
typedef __attribute__((ext_vector_type(4))) float f32x4;
typedef __attribute__((ext_vector_type(8))) __bf16 bf16x8;
typedef __attribute__((ext_vector_type(4))) unsigned short u16x4;
typedef __attribute__((ext_vector_type(8))) unsigned short u16x8;
typedef __attribute__((ext_vector_type(4))) unsigned int u32x4;

// ============================================================================
// LAYOUT CONVENTIONS (write-side must match read-side):
// * bf16 matrices are stored in global PRE-SWIZZLED: within each 64-element
//   (128B) k-slice of a row l, the 16B block b sits at position b ^ (l&7).
//   A fragment reader (lane c,g; k-half kk) reads the 16B at position
//   (kk*4+g) ^ (c&7); fragment rows ≡ c (mod 8) so this yields block kk*4+g.
// * Q/K projections store head features in SLOT order s = 4*(d&15) + (d>>4).
//   Q and K share the permutation => dot products unchanged.  V stored same
//   way; transpose_v un-permutes.  cat uses the same slot order per head,
//   compensated by permuting W_O's input columns.
// * v_T ([bh][d][2048]) position y within each 64-chunk holds physical key
//   nu(y) = (y>>5)*32 + ((y>>2)&1)*16 + ((y>>3)&3)*4 + (y&3), so the PV
//   A-fragment equals exp2(sf[..]) of the SAME lane after swapped QK^T.
// * Fixed-max softmax (hyperboloid: scores<=0) => split-KV partials combine
//   by pure addition; Lorentz normalize is scale-invariant => no denominator.
// * gemm_qkv AND attn_mfma are BARRIER-FREE and LDS-FREE: fragments loaded
//   per-lane directly from swizzled global.  gemm_qkv's k-loop is ROLLED —
//   r14 showed full unroll degrades the compiler's load/MFMA interleave
//   (48 -> 68 us).  attn uses 64 q-rows/wave (r14, ~26 us).
// ============================================================================

__device__ __forceinline__ u16 f2bf(float f) {
    union { float f; unsigned u; } cv; cv.f = f;
    unsigned u = cv.u + 0x7fffu + ((cv.u >> 16) & 1u);
    return (u16)(u >> 16);
}
__device__ __forceinline__ float bf2f(u16 h) {
    union { unsigned u; float f; } cv; cv.u = ((unsigned)h) << 16;
    return cv.f;
}

__device__ __forceinline__ u32 pkbf(float a, float b) {
    union { __bf16 h[2]; u32 u; } cv;
    cv.h[0] = (__bf16)a; cv.h[1] = (__bf16)b;
    return cv.u;
}

// native exp2: inputs here are in [-50, 0.5] -> normal results.
#if __has_builtin(__builtin_amdgcn_exp2f)
__device__ __forceinline__ float exp2_fast(float x) {
    return __builtin_amdgcn_exp2f(x);
}
#else
__device__ __forceinline__ float exp2_fast(float x) {
    float r;
    asm("v_exp_f32 %0, %1" : "=v"(r) : "v"(x));
    return r;
}
#endif

// DPP cross-lane (16-lane row) sum — VALU pipe, no LDS
template <int CTRL>
__device__ __forceinline__ float dppf(float x) {
    return __int_as_float(__builtin_amdgcn_update_dpp(
        0, __float_as_int(x), CTRL, 0xf, 0xf, true));
}
__device__ __forceinline__ float red16_add(float x) {
    x += dppf<0xB1>(x);    // quad_perm(1,0,3,2)
    x += dppf<0x4E>(x);    // quad_perm(2,3,0,1)
    x += dppf<0x141>(x);   // row_half_mirror
    x += dppf<0x140>(x);   // row_mirror
    return x;
}

__device__ __forceinline__ void gload16(const void* g, void* l) {
    __builtin_amdgcn_global_load_lds(
        (const __attribute__((address_space(1))) unsigned int*)g,
        (__attribute__((address_space(3))) unsigned int*)l, 16, 0, 0);
}

// ---------------------------------------------------------------------------
// f32 -> bf16 convert of the 3 inputs, swizzled global layout (rows of 1024).
// ---------------------------------------------------------------------------
__global__ __launch_bounds__(256)
void cvt_in3(const float* __restrict__ i0, const float* __restrict__ i1,
             const float* __restrict__ i2,
             u16* __restrict__ o0, u16* __restrict__ o1, u16* __restrict__ o2)
{
    const int z = blockIdx.y;
    const float* in = z == 0 ? i0 : (z == 1 ? i1 : i2);
    u16* out       = z == 0 ? o0 : (z == 1 ? o1 : o2);
    int i = blockIdx.x * 256 + threadIdx.x;        // group of 4 elements
    f32x4 v = ((const f32x4*)in)[i];
    u16x4 o;
#pragma unroll
    for (int j = 0; j < 4; ++j) o[j] = f2bf(v[j]);
    int l = i >> 8;                // row
    int e = (i & 255) * 4;         // element within row
    int idx = l * 1024 + (e & ~63) + (((((e >> 3) & 7) ^ (l & 7))) << 3) + (e & 7);
    *(u16x4*)&out[idx] = o;
}

// ---------------------------------------------------------------------------
// Weights cvt: wq/wk/wv plain swizzle; wo (z==3) also permutes input columns
// to cat's per-head slot order.
// ---------------------------------------------------------------------------
__global__ __launch_bounds__(256)
void cvt_w(const float* __restrict__ w0, const float* __restrict__ w1,
           const float* __restrict__ w2, const float* __restrict__ w3,
           u16* __restrict__ q0, u16* __restrict__ q1,
           u16* __restrict__ q2, u16* __restrict__ q3)
{
    const int z = blockIdx.y;
    int i = blockIdx.x * 256 + threadIdx.x;
    if (z < 3) {
        const float* in = z == 0 ? w0 : (z == 1 ? w1 : w2);
        u16* out       = z == 0 ? q0 : (z == 1 ? q1 : q2);
        f32x4 v = ((const f32x4*)in)[i];
        u16x4 o;
#pragma unroll
        for (int j = 0; j < 4; ++j) o[j] = f2bf(v[j]);
        int l = i >> 8;
        int e = (i & 255) * 4;
        int idx = l * 1024 + (e & ~63) + (((((e >> 3) & 7) ^ (l & 7))) << 3) + (e & 7);
        *(u16x4*)&out[idx] = o;
    } else {
        int o  = i >> 8;             // output row of W_O (natural)
        int s0 = (i & 255) * 4;      // out column-slot base
        int h = s0 >> 6, sl = s0 & 63, a = sl >> 2;
        const float* src = w3 + (size_t)o * 1024 + h * 64;
        // slot s0+j holds input feature h*64 + j*16 + a
        u16x4 ov = { f2bf(src[a]), f2bf(src[16 + a]),
                     f2bf(src[32 + a]), f2bf(src[48 + a]) };
        int idx = o * 1024 + h * 64 + (((sl >> 3) ^ (o & 7)) << 3) + (sl & 7);
        *(u16x4*)&q3[idx] = ov;
    }
}

// ---------------------------------------------------------------------------
// Q/K/V projection GEMM + fused per-head Lorentz projection.
// 128x128 tile, 4 waves (64x64/wave, acc 4x4).  BARRIER-FREE, LDS-FREE:
// per-lane fragment loads from swizzled global, register-dbuf one kk-step
// ahead; ROLLED k-loop (r13 schedule — full unroll regressed in r14).
// 768 blocks (id: m=id&31 [XCD=m&7], n=(id>>5)&7, z=id>>8) -> 3 blocks/CU.
// Output bf16 [b][h][l][64slots], slot-permuted + byte-swizzled.
// ---------------------------------------------------------------------------
__global__ __launch_bounds__(256)
void gemm_qkv(const u16* __restrict__ xq, const u16* __restrict__ xk,
              const u16* __restrict__ xv, const u16* __restrict__ wq,
              const u16* __restrict__ wk, const u16* __restrict__ wv,
              const float* __restrict__ bq, const float* __restrict__ bk,
              const float* __restrict__ bv,
              u16* __restrict__ oq, u16* __restrict__ ok, u16* __restrict__ ov)
{
    const int t = threadIdx.x;
    const int lane = t & 63, w = t >> 6;
    const int g = lane >> 4, c = lane & 15;
    const int wr = w >> 1, wc = w & 1;
    const int id = blockIdx.x;
    const int bm = (id & 31) * 128;
    const int bn = ((id >> 5) & 7) * 128;
    const int z  = id >> 8;

    const u16* A = z == 0 ? xq : (z == 1 ? xk : xv);
    const u16* W = z == 0 ? wq : (z == 1 ? wk : wv);
    const float* bias = z == 0 ? bq : (z == 1 ? bk : bv);
    u16* Ct = z == 0 ? oq : (z == 1 ? ok : ov);
    const float scale = z == 0 ? QSCALE : 1.f;
    const float tsign = z == 0 ? -1.f : 1.f;

    // per-lane fragment bases (rows ≡ c mod 8 -> swizzle XOR uses c&7)
    const int s7 = c & 7;
    const int ko0 = ((0 + g) ^ s7) << 3;     // kk=0 elem offset in 64-slice
    const int ko1 = ((4 + g) ^ s7) << 3;     // kk=1
    const u16* Ab[4];
    const u16* Bb[4];
#pragma unroll
    for (int mi = 0; mi < 4; ++mi)
        Ab[mi] = A + (size_t)(bm + wr * 64 + mi * 16 + c) * Dn;
#pragma unroll
    for (int ni = 0; ni < 4; ++ni)
        Bb[ni] = W + (size_t)(bn + wc * 64 + ni * 16 + c) * Dn;

    f32x4 acc[4][4];
    const f32x4 z4 = {0.f, 0.f, 0.f, 0.f};
#pragma unroll
    for (int i = 0; i < 4; ++i)
#pragma unroll
        for (int j = 0; j < 4; ++j) acc[i][j] = z4;

    bf16x8 a0[4], b0[4], a1[4], b1[4];
#pragma unroll
    for (int mi = 0; mi < 4; ++mi) a0[mi] = *(const bf16x8*)(Ab[mi] + ko0);
#pragma unroll
    for (int ni = 0; ni < 4; ++ni) b0[ni] = *(const bf16x8*)(Bb[ni] + ko0);

    for (int ki = 0; ki < 16; ++ki) {
        const int kb = ki * 64;
        // prefetch kk=1 of this k-tile
#pragma unroll
        for (int mi = 0; mi < 4; ++mi) a1[mi] = *(const bf16x8*)(Ab[mi] + kb + ko1);
#pragma unroll
        for (int ni = 0; ni < 4; ++ni) b1[ni] = *(const bf16x8*)(Bb[ni] + kb + ko1);
        __builtin_amdgcn_s_setprio(1);
#pragma unroll
        for (int mi = 0; mi < 4; ++mi)
#pragma unroll
            for (int ni = 0; ni < 4; ++ni)
                acc[mi][ni] = __builtin_amdgcn_mfma_f32_16x16x32_bf16(
                    a0[mi], b0[ni], acc[mi][ni], 0, 0, 0);
        __builtin_amdgcn_s_setprio(0);
        if (ki + 1 < 16) {   // prefetch kk=0 of next k-tile
#pragma unroll
            for (int mi = 0; mi < 4; ++mi)
                a0[mi] = *(const bf16x8*)(Ab[mi] + kb + 64 + ko0);
#pragma unroll
            for (int ni = 0; ni < 4; ++ni)
                b0[ni] = *(const bf16x8*)(Bb[ni] + kb + 64 + ko0);
        }
        __builtin_amdgcn_s_setprio(1);
#pragma unroll
        for (int mi = 0; mi < 4; ++mi)
#pragma unroll
            for (int ni = 0; ni < 4; ++ni)
                acc[mi][ni] = __builtin_amdgcn_mfma_f32_16x16x32_bf16(
                    a1[mi], b1[ni], acc[mi][ni], 0, 0, 0);
        __builtin_amdgcn_s_setprio(0);
    }

    // fused per-head Lorentz projection epilogue (verified in r12)
    const int hcb = bn + wc * 64;
    const int h = hcb >> 6;
#pragma unroll
    for (int mi = 0; mi < 4; ++mi)
#pragma unroll
        for (int j = 0; j < 4; ++j) {
            int ll = bm + wr * 64 + mi * 16 + g * 4 + j;
            float zv[4];
#pragma unroll
            for (int ni = 0; ni < 4; ++ni)
                zv[ni] = acc[mi][ni][j] + bias[hcb + ni * 16 + c];
            float loc = zv[0]*zv[0] + zv[1]*zv[1] + zv[2]*zv[2] + zv[3]*zv[3];
            if (c == 0) loc -= zv[0] * zv[0];     // z0 is DISCARDED (once!)
            loc = red16_add(loc);                 // = sum of space^2
            float tval = sqrtf(1.f + loc);
            float v0 = (c == 0) ? tsign * tval : zv[0];
            int bb = ll >> 11, l2 = ll & 2047;
            u16* dst = Ct + (((size_t)bb * 16 + h) * Ln + l2) * 64;
            u16x4 pkv = { f2bf(v0 * scale), f2bf(zv[1] * scale),
                          f2bf(zv[2] * scale), f2bf(zv[3] * scale) };
            *(u16x4*)&dst[(4 * c) ^ ((ll & 7) << 3)] = pkv;
        }
}

// ---------------------------------------------------------------------------
// V transpose: [bh][l][64 slots,swz] -> v_T [bh][d][2048] where position y
// within each 64-chunk holds key nu(y) (see header), byte-swizzled per (d&7).
// ---------------------------------------------------------------------------
__global__ __launch_bounds__(256)
void transpose_v(const u16* __restrict__ vin, u16* __restrict__ vout)
{
    __shared__ u16 raw[64 * 64];     // straight copy of the swizzled tile
    const int t = threadIdx.x;
    const int bh = blockIdx.x, lc = blockIdx.y;
    const u16* src = vin + ((size_t)bh * Ln + lc * 64) * 64;
#pragma unroll
    for (int p = 0; p < 2; ++p) {
        int ci = p * 256 + t;
        *(u16x8*)&raw[ci * 8] = *(const u16x8*)(src + ci * 8);
    }
    __syncthreads();
    const int d = t >> 2, cp0 = (t & 3) * 16;
    const int s = ((d & 15) << 2) | (d >> 4);   // slot of true feature d
    u16 buf[16];
#pragma unroll
    for (int i = 0; i < 16; ++i) {
        int cp = cp0 + i;
        // physical key for v_T position cp:
        int n = ((cp >> 5) << 5) | (((cp >> 2) & 1) << 4) | (((cp >> 3) & 3) << 2) | (cp & 3);
        buf[i] = raw[n * 64 + ((((s >> 3) ^ (n & 7)) << 3) | (s & 7))];
    }
    u16* dst = vout + ((size_t)bh * 64 + d) * Ln + lc * 64;
    int b0 = cp0 >> 3;
    *(u16x8*)&dst[((b0 ^ (d & 7)) << 3)]       = *(const u16x8*)&buf[0];
    *(u16x8*)&dst[(((b0 + 1) ^ (d & 7)) << 3)] = *(const u16x8*)&buf[8];
}

// ---------------------------------------------------------------------------
// Split-KV MFMA flash attention, BARRIER-FREE / LDS-FREE.  512 blocks
// (id: XCD grp = id&7, qb = (id>>3)&7, gidx = (id&7)|((id>>6)<<3)):
// block = 256 q-rows x 1024 keys; 4 waves x 64 q-rows/wave.  K/V fragments
// loaded per-lane directly from swizzled global (shared K/V chunk -> L1
// hits across waves).  Swapped QK^T, in-register P, fixed-max softmax,
// no denominator.  Writes bf16 PARTIAL O; halves add in attn_combine.
// ---------------------------------------------------------------------------
__global__ __launch_bounds__(256)
void attn_mfma(const u16* __restrict__ qt, const u16* __restrict__ kt,
               const u16* __restrict__ vT, u16* __restrict__ part)
{
    const int t = threadIdx.x;
    const int lane = t & 63, w = t >> 6;
    const int g = lane >> 4, c = lane & 15;
    const int id  = blockIdx.x;
    const int qb  = (id >> 3) & 7;
    const int gidx = (id & 7) | ((id >> 6) << 3);   // 0..63
    const int bh  = gidx & 31;
    const int kvh = gidx >> 5;
    const int q0  = qb * 256;
    const u16* Q = qt + (size_t)bh * Ln * 64;
    const u16* K = kt + (size_t)bh * Ln * 64 + (size_t)kvh * (1024 * 64);
    const u16* V = vT + (size_t)bh * 64 * (size_t)Ln + kvh * 1024;

    const int s7 = c & 7;
    const int ko0 = ((0 + g) ^ s7) << 3;
    const int ko1 = ((4 + g) ^ s7) << 3;

    // Q fragments (4 row-frags x 2 k-halves) in registers for the whole sweep
    bf16x8 qa[4][2];
#pragma unroll
    for (int mi = 0; mi < 4; ++mi) {
        int row = q0 + w * 64 + mi * 16 + c;
        qa[mi][0] = *(const bf16x8*)(Q + (size_t)row * 64 + ko0);
        qa[mi][1] = *(const bf16x8*)(Q + (size_t)row * 64 + ko1);
    }

    // K row-bases (rows ni*16+c) and V row-bases (rows di*16+c)
    const u16* KB[4];
    const u16* VB[4];
#pragma unroll
    for (int ni = 0; ni < 4; ++ni) KB[ni] = K + (size_t)(ni * 16 + c) * 64;
#pragma unroll
    for (int di = 0; di < 4; ++di) VB[di] = V + (size_t)(di * 16 + c) * Ln;

    f32x4 o[4][4];
    const f32x4 z4 = {0.f, 0.f, 0.f, 0.f};
#pragma unroll
    for (int mi = 0; mi < 4; ++mi)
#pragma unroll
        for (int di = 0; di < 4; ++di) o[mi][di] = z4;

    for (int ch = 0; ch < 16; ++ch) {
        const int kof = ch * 4096;   // 64 rows * 64 elems per chunk
        const int vof = ch * 64;     // 64 positions per chunk

        // ---- QK^T swapped: sf[mi][ni][j] = S[k=16ni+4g+j][q=16mi+c] ----
        f32x4 sf[4][4];
#pragma unroll
        for (int mi = 0; mi < 4; ++mi)
#pragma unroll
            for (int ni = 0; ni < 4; ++ni) sf[mi][ni] = z4;
#pragma unroll
        for (int kk = 0; kk < 2; ++kk) {
            const int ko = kk ? ko1 : ko0;
            bf16x8 kb[4];
#pragma unroll
            for (int ni = 0; ni < 4; ++ni)
                kb[ni] = *(const bf16x8*)(KB[ni] + kof + ko);
            __builtin_amdgcn_s_setprio(1);
#pragma unroll
            for (int mi = 0; mi < 4; ++mi)
#pragma unroll
                for (int ni = 0; ni < 4; ++ni)
                    sf[mi][ni] = __builtin_amdgcn_mfma_f32_16x16x32_bf16(
                        kb[ni], qa[mi][kk], sf[mi][ni], 0, 0, 0);
            __builtin_amdgcn_s_setprio(0);
        }

        // ---- softmax numerator (fixed max 0) + P frags in registers ----
        bf16x8 paf[4][2];
#pragma unroll
        for (int mi = 0; mi < 4; ++mi) {
            float ex[4][4];
#pragma unroll
            for (int ni = 0; ni < 4; ++ni)
#pragma unroll
                for (int j = 0; j < 4; ++j)
                    ex[ni][j] = exp2_fast(sf[mi][ni][j]);
            u32x4 p0 = { pkbf(ex[0][0], ex[0][1]), pkbf(ex[0][2], ex[0][3]),
                         pkbf(ex[1][0], ex[1][1]), pkbf(ex[1][2], ex[1][3]) };
            u32x4 p1 = { pkbf(ex[2][0], ex[2][1]), pkbf(ex[2][2], ex[2][3]),
                         pkbf(ex[3][0], ex[3][1]), pkbf(ex[3][2], ex[3][3]) };
            paf[mi][0] = __builtin_bit_cast(bf16x8, p0);
            paf[mi][1] = __builtin_bit_cast(bf16x8, p1);
        }

        // ---- PV (32 MFMA): O[q][d] += P[q][k] V[k][d] ----
#pragma unroll
        for (int kk = 0; kk < 2; ++kk) {
            const int ko = kk ? ko1 : ko0;
            bf16x8 vb[4];
#pragma unroll
            for (int di = 0; di < 4; ++di)
                vb[di] = *(const bf16x8*)(VB[di] + vof + ko);
            __builtin_amdgcn_s_setprio(1);
#pragma unroll
            for (int di = 0; di < 4; ++di)
#pragma unroll
                for (int mi = 0; mi < 4; ++mi)
                    o[mi][di] = __builtin_amdgcn_mfma_f32_16x16x32_bf16(
                        paf[mi][kk], vb[di], o[mi][di], 0, 0, 0);
            __builtin_amdgcn_s_setprio(0);
        }
    }

    // ---- epilogue: store bf16 partial O ----
    u16* P = part + (size_t)(kvh * 32 + bh) * (4 * 2048 * 16);
#pragma unroll
    for (int mi = 0; mi < 4; ++mi)
#pragma unroll
        for (int j = 0; j < 4; ++j) {
            int row = q0 + w * 64 + mi * 16 + g * 4 + j;
#pragma unroll
            for (int di = 0; di < 4; ++di)
                P[(di * 2048 + row) * 16 + c] = f2bf(o[mi][di][j]);
        }
}

// ---------------------------------------------------------------------------
// Combine the two KV-half partials, Lorentz-normalize per head row, write
// bf16 cat (slot order + swizzle).  16-lane group per (bh,q) row.
// ---------------------------------------------------------------------------
__global__ __launch_bounds__(256)
void attn_combine(const u16* __restrict__ part, u16* __restrict__ cat)
{
    const int grp = blockIdx.x * 16 + (threadIdx.x >> 4);  // row id in [0,65536)
    const int c = threadIdx.x & 15;
    const int bh = grp >> 11, q = grp & 2047;
    const u16* P0 = part + (size_t)bh * (4 * 2048 * 16);
    const u16* P1 = part + (size_t)(32 + bh) * (4 * 2048 * 16);
    float mu[4];
#pragma unroll
    for (int di = 0; di < 4; ++di) {
        int idx = (di * 2048 + q) * 16 + c;
        mu[di] = bf2f(P0[idx]) + bf2f(P1[idx]);
    }
    float loc = mu[0]*mu[0] + mu[1]*mu[1] + mu[2]*mu[2] + mu[3]*mu[3];
    if (c == 0) loc -= 2.f * mu[0] * mu[0];   // Lorentz inner <o,o>
    loc = red16_add(loc);
    float rn = rsqrtf(fmaxf(fabsf(loc), 1e-6f));
    const int b = bh >> 4, h = bh & 15;
    u16* dst = cat + ((size_t)b * Ln + q) * Dn + h * 64;
    u16x4 pkv = { f2bf(mu[0] * rn), f2bf(mu[1] * rn),
                  f2bf(mu[2] * rn), f2bf(mu[3] * rn) };
    *(u16x4*)&dst[(4 * c) ^ ((q & 7) << 3)] = pkv;
}

// ---------------------------------------------------------------------------
// Output GEMM: out[4096][1024] = cat @ wo^T + b_O (f32 out).
// 64x128 tile, BK=64, double-buffered (48 KB), XCD-swizzled 512 blocks.
// (round-10 proven structure)
// ---------------------------------------------------------------------------
__global__ __launch_bounds__(256)
void gemm_o(const u16* __restrict__ A, const u16* __restrict__ B,
            const float* __restrict__ bias, float* __restrict__ C)
{
    __shared__ u16 As[2][64 * 64];
    __shared__ u16 Bs[2][128 * 64];
    const int t = threadIdx.x;
    const int lane = t & 63, w = t >> 6;
    const int g = lane >> 4, c = lane & 15;
    const int wr = w >> 1, wc = w & 1;
    // XCD decode: y = (id&7)*8 + ((id>>3)&7) in [0,64), x = id>>6 in [0,8)
    const int id = blockIdx.x;
    const int bm = ((id & 7) * 8 + ((id >> 3) & 7)) * 64;
    const int bn = (id >> 6) * 128;

    f32x4 acc[2][4];
    const f32x4 z4 = {0.f, 0.f, 0.f, 0.f};
#pragma unroll
    for (int i = 0; i < 2; ++i)
#pragma unroll
        for (int j = 0; j < 4; ++j) acc[i][j] = z4;

    const int sr = t >> 3, sb2 = (t & 7) * 8;
    const u16* Ap = A + (size_t)(bm + sr) * Dn + sb2;
    const u16* Bp = B + (size_t)(bn + sr) * Dn + sb2;

    auto stage = [&](int buf, int k0) {
        gload16(Ap + k0,            &As[buf][t * 8]);
        gload16(Ap + 32 * Dn + k0,  &As[buf][(256 + t) * 8]);
        gload16(Bp + k0,            &Bs[buf][t * 8]);
        gload16(Bp + 32 * Dn + k0,  &Bs[buf][(256 + t) * 8]);
        gload16(Bp + 64 * Dn + k0,  &Bs[buf][(512 + t) * 8]);
        gload16(Bp + 96 * Dn + k0,  &Bs[buf][(768 + t) * 8]);
    };

    stage(0, 0);
    for (int ki = 0; ki < 16; ++ki) {
        __syncthreads();
        if (ki + 1 < 16) stage((ki + 1) & 1, (ki + 1) * 64);
        const u16* as = As[ki & 1];
        const u16* bs = Bs[ki & 1];
#pragma unroll
        for (int kk = 0; kk < 2; ++kk) {
            const int so = ((kk * 4 + g) ^ (c & 7)) << 3;
            bf16x8 a[2], b[4];
#pragma unroll
            for (int mi = 0; mi < 2; ++mi)
                a[mi] = *(const bf16x8*)&as[(wr * 32 + mi * 16 + c) * 64 + so];
#pragma unroll
            for (int ni = 0; ni < 4; ++ni)
                b[ni] = *(const bf16x8*)&bs[(wc * 64 + ni * 16 + c) * 64 + so];
            __builtin_amdgcn_s_setprio(1);
#pragma unroll
            for (int mi = 0; mi < 2; ++mi)
#pragma unroll
                for (int ni = 0; ni < 4; ++ni)
                    acc[mi][ni] = __builtin_amdgcn_mfma_f32_16x16x32_bf16(
                        a[mi], b[ni], acc[mi][ni], 0, 0, 0);
            __builtin_amdgcn_s_setprio(0);
        }
    }

#pragma unroll
    for (int mi = 0; mi < 2; ++mi)
#pragma unroll
        for (int j = 0; j < 4; ++j) {
            size_t row = bm + wr * 32 + mi * 16 + g * 4 + j;
#pragma unroll
            for (int ni = 0; ni < 4; ++ni) {
                int col = bn + wc * 64 + ni * 16 + c;
                C[row * Dn + col] = acc[mi][ni][j] + bias[col];
            }
        }
}

// ---------------------------------------------------------------------------
// Full-row (D=1024) Lorentz projection on f32 output rows.
// ---------------------------------------------------------------------------
__global__ __launch_bounds__(256)
void lorentz_row_full(float* __restrict__ z)
{
    __shared__ float red[4];
    const int t = threadIdx.x;
    const size_t base = (size_t)blockIdx.x * Dn;
    float4 v = *(const float4*)&z[base + t * 4];
    if (t == 0) v.x = 0.f;
    float ssq = v.x * v.x + v.y * v.y + v.z * v.z + v.w * v.w;
#pragma unroll
    for (int off = 32; off; off >>= 1) ssq += __shfl_xor(ssq, off);
    if ((t & 63) == 0) red[t >> 6] = ssq;
    __syncthreads();
    if (t == 0) z[base] = sqrtf(1.0f + red[0] + red[1] + red[2] + red[3]);
}

// ---------------------------------------------------------------------------
extern "C" void kernel_launch(void* const* d_in, const int* in_sizes, int n_in,
                              void* d_out, int out_size, void* d_ws, size_t ws_size,
                              hipStream_t stream)
{
    const float* query = (const float*)d_in[0];
    const float* key_  = (const float*)d_in[1];
    const float* value = (const float*)d_in[2];
    const float* W_Q   = (const float*)d_in[3];
    const float* b_Q   = (const float*)d_in[4];
    const float* W_K   = (const float*)d_in[5];
    const float* b_K   = (const float*)d_in[6];
    const float* W_V   = (const float*)d_in[7];
    const float* b_V   = (const float*)d_in[8];
    const float* W_O   = (const float*)d_in[9];
    const float* b_O   = (const float*)d_in[10];

    // ws layout (u16 elems; 64 MiB budget).  part aliases wq/wk/wv/v_ln,
    // all of which are dead before attn_mfma runs.
    const size_t MD = (size_t)Mn * Dn;   // 4M elems (8 MiB)
    const size_t DD = (size_t)Dn * Dn;   // 1M elems (2 MiB)
    u16* xq   = (u16*)d_ws;              //  0M..4M   swz input q
    u16* xk   = xq + MD;                 //  4M..8M   swz input k
    u16* xv   = xk + MD;                 //  8M..12M  swz input v
    u16* wo   = xv + MD;                 // 12M..13M  W_O (swz + col perm)
    u16* q_t  = wo + DD;                 // 13M..17M  [b][h][l][64slots]
    u16* k_t  = q_t + MD;                // 17M..21M
    u16* wq   = k_t + MD;                // 21M..22M
    u16* wk   = wq + DD;                 // 22M..23M
    u16* wv   = wk + DD;                 // 23M..24M
    u16* v_ln = wv + DD;                 // 24M..28M  V projection
    u16* part = wq;                      // 21M..29M  bf16 partials (16 MiB)
    u16* v_T  = xv;                      // alias: xv dead after gemm_qkv
    u16* cat  = xk;                      // alias: xk dead after gemm_qkv

    dim3 ci(Mn * Dn / 1024, 3);                // (4096, 3)
    cvt_in3<<<ci, 256, 0, stream>>>(query, key_, value, xq, xk, xv);
    dim3 cw(Dn * Dn / 1024, 4);                // (1024, 4)
    cvt_w<<<cw, 256, 0, stream>>>(W_Q, W_K, W_V, W_O, wq, wk, wv, wo);

    gemm_qkv<<<768, 256, 0, stream>>>(xq, xk, xv, wq, wk, wv,
                                      b_Q, b_K, b_V, q_t, k_t, v_ln);

    dim3 tg(32, Ln / 64);                      // (32, 32)
    transpose_v<<<tg, 256, 0, stream>>>(v_ln, v_T);

    attn_mfma<<<512, 256, 0, stream>>>(q_t, k_t, v_T, part);  // XCD-swizzled 1D

    attn_combine<<<4096, 256, 0, stream>>>(part, cat);

    gemm_o<<<512, 256, 0, stream>>>(cat, wo, b_O, (float*)d_out);
    lorentz_row_full<<<Mn, 256, 0, stream>>>((float*)d_out);
}

// Round 16
// 129.260 us; speedup vs baseline: 1.0619x; 1.0607x over previous
//
#include <hip/hip_runtime.h>
#include <math.h>

namespace {
constexpr int Ln = 2048;
constexpr int Dn = 1024;
constexpr int Mn = 4096;   // B*L
constexpr float QSCALE = 0.25f * 1.44269504088896340736f; // 2/sqrt(64) * log2(e)
}

typedef unsigned short u16;
typedef unsigned int u32;
typedef __attribute__((ext_vector_type(4))) float f32x4;
typedef __attribute__((ext_vector_type(8))) __bf16 bf16x8;
typedef __attribute__((ext_vector_type(4))) unsigned short u16x4;
typedef __attribute__((ext_vector_type(8))) unsigned short u16x8;
typedef __attribute__((ext_vector_type(4))) unsigned int u32x4;

// ============================================================================
// LAYOUT CONVENTIONS (write-side must match read-side):
// * bf16 matrices are stored in global PRE-SWIZZLED: within each 64-element
//   (128B) k-slice of a row l, the 16B block b sits at position b ^ (l&7).
//   A fragment reader (lane c,g; k-half kk) reads the 16B at position
//   (kk*4+g) ^ (c&7); fragment rows ≡ c (mod 8) so this yields block kk*4+g.
// * Q/K projections store head features in SLOT order s = 4*(d&15) + (d>>4).
//   Q and K share the permutation => dot products unchanged.  V stored same
//   way; transpose_v un-permutes.  cat uses the same slot order per head,
//   compensated by permuting W_O's input columns.
// * v_T ([bh][d][2048]) position y within each 64-chunk holds physical key
//   nu(y) = (y>>5)*32 + ((y>>2)&1)*16 + ((y>>3)&3)*4 + (y&3), so the PV
//   A-fragment equals exp2(sf[..]) of the SAME lane after swapped QK^T.
// * Fixed-max softmax (hyperboloid: scores<=0) => split-KV partials combine
//   by pure addition; Lorentz normalize is scale-invariant => no denominator.
// * gemm_qkv is BARRIER-FREE/LDS-FREE (rolled k-loop; full unroll regressed
//   in r14).  attn_mfma is the LDS split-KV version (r13) — the r14/r15
//   barrier-free attn regressed 43->60 us (per-wave K/V re-fetch + addr VALU).
// ============================================================================

__device__ __forceinline__ u16 f2bf(float f) {
    union { float f; unsigned u; } cv; cv.f = f;
    unsigned u = cv.u + 0x7fffu + ((cv.u >> 16) & 1u);
    return (u16)(u >> 16);
}
__device__ __forceinline__ float bf2f(u16 h) {
    union { unsigned u; float f; } cv; cv.u = ((unsigned)h) << 16;
    return cv.f;
}

__device__ __forceinline__ u32 pkbf(float a, float b) {
    union { __bf16 h[2]; u32 u; } cv;
    cv.h[0] = (__bf16)a; cv.h[1] = (__bf16)b;
    return cv.u;
}

// native exp2: inputs here are in [-50, 0.5] -> normal results.
#if __has_builtin(__builtin_amdgcn_exp2f)
__device__ __forceinline__ float exp2_fast(float x) {
    return __builtin_amdgcn_exp2f(x);
}
#else
__device__ __forceinline__ float exp2_fast(float x) {
    float r;
    asm("v_exp_f32 %0, %1" : "=v"(r) : "v"(x));
    return r;
}
#endif

// DPP cross-lane (16-lane row) sum — VALU pipe, no LDS
template <int CTRL>
__device__ __forceinline__ float dppf(float x) {
    return __int_as_float(__builtin_amdgcn_update_dpp(
        0, __float_as_int(x), CTRL, 0xf, 0xf, true));
}
__device__ __forceinline__ float red16_add(float x) {
    x += dppf<0xB1>(x);    // quad_perm(1,0,3,2)
    x += dppf<0x4E>(x);    // quad_perm(2,3,0,1)
    x += dppf<0x141>(x);   // row_half_mirror
    x += dppf<0x140>(x);   // row_mirror
    return x;
}

__device__ __forceinline__ void gload16(const void* g, void* l) {
    __builtin_amdgcn_global_load_lds(
        (const __attribute__((address_space(1))) unsigned int*)g,
        (__attribute__((address_space(3))) unsigned int*)l, 16, 0, 0);
}

// ---------------------------------------------------------------------------
// f32 -> bf16 convert of the 3 inputs, swizzled global layout (rows of 1024).
// ---------------------------------------------------------------------------
__global__ __launch_bounds__(256)
void cvt_in3(const float* __restrict__ i0, const float* __restrict__ i1,
             const float* __restrict__ i2,
             u16* __restrict__ o0, u16* __restrict__ o1, u16* __restrict__ o2)
{
    const int z = blockIdx.y;
    const float* in = z == 0 ? i0 : (z == 1 ? i1 : i2);
    u16* out       = z == 0 ? o0 : (z == 1 ? o1 : o2);
    int i = blockIdx.x * 256 + threadIdx.x;        // group of 4 elements
    f32x4 v = ((const f32x4*)in)[i];
    u16x4 o;
#pragma unroll
    for (int j = 0; j < 4; ++j) o[j] = f2bf(v[j]);
    int l = i >> 8;                // row
    int e = (i & 255) * 4;         // element within row
    int idx = l * 1024 + (e & ~63) + (((((e >> 3) & 7) ^ (l & 7))) << 3) + (e & 7);
    *(u16x4*)&out[idx] = o;
}

// ---------------------------------------------------------------------------
// Weights cvt: wq/wk/wv plain swizzle; wo (z==3) also permutes input columns
// to cat's per-head slot order.
// ---------------------------------------------------------------------------
__global__ __launch_bounds__(256)
void cvt_w(const float* __restrict__ w0, const float* __restrict__ w1,
           const float* __restrict__ w2, const float* __restrict__ w3,
           u16* __restrict__ q0, u16* __restrict__ q1,
           u16* __restrict__ q2, u16* __restrict__ q3)
{
    const int z = blockIdx.y;
    int i = blockIdx.x * 256 + threadIdx.x;
    if (z < 3) {
        const float* in = z == 0 ? w0 : (z == 1 ? w1 : w2);
        u16* out       = z == 0 ? q0 : (z == 1 ? q1 : q2);
        f32x4 v = ((const f32x4*)in)[i];
        u16x4 o;
#pragma unroll
        for (int j = 0; j < 4; ++j) o[j] = f2bf(v[j]);
        int l = i >> 8;
        int e = (i & 255) * 4;
        int idx = l * 1024 + (e & ~63) + (((((e >> 3) & 7) ^ (l & 7))) << 3) + (e & 7);
        *(u16x4*)&out[idx] = o;
    } else {
        int o  = i >> 8;             // output row of W_O (natural)
        int s0 = (i & 255) * 4;      // out column-slot base
        int h = s0 >> 6, sl = s0 & 63, a = sl >> 2;
        const float* src = w3 + (size_t)o * 1024 + h * 64;
        // slot s0+j holds input feature h*64 + j*16 + a
        u16x4 ov = { f2bf(src[a]), f2bf(src[16 + a]),
                     f2bf(src[32 + a]), f2bf(src[48 + a]) };
        int idx = o * 1024 + h * 64 + (((sl >> 3) ^ (o & 7)) << 3) + (sl & 7);
        *(u16x4*)&q3[idx] = ov;
    }
}

// ---------------------------------------------------------------------------
// Q/K/V projection GEMM + fused per-head Lorentz projection.
// 128x128 tile, 4 waves (64x64/wave, acc 4x4).  BARRIER-FREE, LDS-FREE:
// per-lane fragment loads from swizzled global, register-dbuf one kk-step
// ahead; ROLLED k-loop (r13 schedule — full unroll regressed in r14).
// 768 blocks (id: m=id&31 [XCD=m&7], n=(id>>5)&7, z=id>>8) -> 3 blocks/CU.
// Output bf16 [b][h][l][64slots], slot-permuted + byte-swizzled.
// ---------------------------------------------------------------------------
__global__ __launch_bounds__(256)
void gemm_qkv(const u16* __restrict__ xq, const u16* __restrict__ xk,
              const u16* __restrict__ xv, const u16* __restrict__ wq,
              const u16* __restrict__ wk, const u16* __restrict__ wv,
              const float* __restrict__ bq, const float* __restrict__ bk,
              const float* __restrict__ bv,
              u16* __restrict__ oq, u16* __restrict__ ok, u16* __restrict__ ov)
{
    const int t = threadIdx.x;
    const int lane = t & 63, w = t >> 6;
    const int g = lane >> 4, c = lane & 15;
    const int wr = w >> 1, wc = w & 1;
    const int id = blockIdx.x;
    const int bm = (id & 31) * 128;
    const int bn = ((id >> 5) & 7) * 128;
    const int z  = id >> 8;

    const u16* A = z == 0 ? xq : (z == 1 ? xk : xv);
    const u16* W = z == 0 ? wq : (z == 1 ? wk : wv);
    const float* bias = z == 0 ? bq : (z == 1 ? bk : bv);
    u16* Ct = z == 0 ? oq : (z == 1 ? ok : ov);
    const float scale = z == 0 ? QSCALE : 1.f;
    const float tsign = z == 0 ? -1.f : 1.f;

    // per-lane fragment bases (rows ≡ c mod 8 -> swizzle XOR uses c&7)
    const int s7 = c & 7;
    const int ko0 = ((0 + g) ^ s7) << 3;     // kk=0 elem offset in 64-slice
    const int ko1 = ((4 + g) ^ s7) << 3;     // kk=1
    const u16* Ab[4];
    const u16* Bb[4];
#pragma unroll
    for (int mi = 0; mi < 4; ++mi)
        Ab[mi] = A + (size_t)(bm + wr * 64 + mi * 16 + c) * Dn;
#pragma unroll
    for (int ni = 0; ni < 4; ++ni)
        Bb[ni] = W + (size_t)(bn + wc * 64 + ni * 16 + c) * Dn;

    f32x4 acc[4][4];
    const f32x4 z4 = {0.f, 0.f, 0.f, 0.f};
#pragma unroll
    for (int i = 0; i < 4; ++i)
#pragma unroll
        for (int j = 0; j < 4; ++j) acc[i][j] = z4;

    bf16x8 a0[4], b0[4], a1[4], b1[4];
#pragma unroll
    for (int mi = 0; mi < 4; ++mi) a0[mi] = *(const bf16x8*)(Ab[mi] + ko0);
#pragma unroll
    for (int ni = 0; ni < 4; ++ni) b0[ni] = *(const bf16x8*)(Bb[ni] + ko0);

    for (int ki = 0; ki < 16; ++ki) {
        const int kb = ki * 64;
        // prefetch kk=1 of this k-tile
#pragma unroll
        for (int mi = 0; mi < 4; ++mi) a1[mi] = *(const bf16x8*)(Ab[mi] + kb + ko1);
#pragma unroll
        for (int ni = 0; ni < 4; ++ni) b1[ni] = *(const bf16x8*)(Bb[ni] + kb + ko1);
        __builtin_amdgcn_s_setprio(1);
#pragma unroll
        for (int mi = 0; mi < 4; ++mi)
#pragma unroll
            for (int ni = 0; ni < 4; ++ni)
                acc[mi][ni] = __builtin_amdgcn_mfma_f32_16x16x32_bf16(
                    a0[mi], b0[ni], acc[mi][ni], 0, 0, 0);
        __builtin_amdgcn_s_setprio(0);
        if (ki + 1 < 16) {   // prefetch kk=0 of next k-tile
#pragma unroll
            for (int mi = 0; mi < 4; ++mi)
                a0[mi] = *(const bf16x8*)(Ab[mi] + kb + 64 + ko0);
#pragma unroll
            for (int ni = 0; ni < 4; ++ni)
                b0[ni] = *(const bf16x8*)(Bb[ni] + kb + 64 + ko0);
        }
        __builtin_amdgcn_s_setprio(1);
#pragma unroll
        for (int mi = 0; mi < 4; ++mi)
#pragma unroll
            for (int ni = 0; ni < 4; ++ni)
                acc[mi][ni] = __builtin_amdgcn_mfma_f32_16x16x32_bf16(
                    a1[mi], b1[ni], acc[mi][ni], 0, 0, 0);
        __builtin_amdgcn_s_setprio(0);
    }

    // fused per-head Lorentz projection epilogue (verified in r12)
    const int hcb = bn + wc * 64;
    const int h = hcb >> 6;
#pragma unroll
    for (int mi = 0; mi < 4; ++mi)
#pragma unroll
        for (int j = 0; j < 4; ++j) {
            int ll = bm + wr * 64 + mi * 16 + g * 4 + j;
            float zv[4];
#pragma unroll
            for (int ni = 0; ni < 4; ++ni)
                zv[ni] = acc[mi][ni][j] + bias[hcb + ni * 16 + c];
            float loc = zv[0]*zv[0] + zv[1]*zv[1] + zv[2]*zv[2] + zv[3]*zv[3];
            if (c == 0) loc -= zv[0] * zv[0];     // z0 is DISCARDED (once!)
            loc = red16_add(loc);                 // = sum of space^2
            float tval = sqrtf(1.f + loc);
            float v0 = (c == 0) ? tsign * tval : zv[0];
            int bb = ll >> 11, l2 = ll & 2047;
            u16* dst = Ct + (((size_t)bb * 16 + h) * Ln + l2) * 64;
            u16x4 pkv = { f2bf(v0 * scale), f2bf(zv[1] * scale),
                          f2bf(zv[2] * scale), f2bf(zv[3] * scale) };
            *(u16x4*)&dst[(4 * c) ^ ((ll & 7) << 3)] = pkv;
        }
}

// ---------------------------------------------------------------------------
// V transpose: [bh][l][64 slots,swz] -> v_T [bh][d][2048] where position y
// within each 64-chunk holds key nu(y) (see header), byte-swizzled per (d&7).
// ---------------------------------------------------------------------------
__global__ __launch_bounds__(256)
void transpose_v(const u16* __restrict__ vin, u16* __restrict__ vout)
{
    __shared__ u16 raw[64 * 64];     // straight copy of the swizzled tile
    const int t = threadIdx.x;
    const int bh = blockIdx.x, lc = blockIdx.y;
    const u16* src = vin + ((size_t)bh * Ln + lc * 64) * 64;
#pragma unroll
    for (int p = 0; p < 2; ++p) {
        int ci = p * 256 + t;
        *(u16x8*)&raw[ci * 8] = *(const u16x8*)(src + ci * 8);
    }
    __syncthreads();
    const int d = t >> 2, cp0 = (t & 3) * 16;
    const int s = ((d & 15) << 2) | (d >> 4);   // slot of true feature d
    u16 buf[16];
#pragma unroll
    for (int i = 0; i < 16; ++i) {
        int cp = cp0 + i;
        // physical key for v_T position cp:
        int n = ((cp >> 5) << 5) | (((cp >> 2) & 1) << 4) | (((cp >> 3) & 3) << 2) | (cp & 3);
        buf[i] = raw[n * 64 + ((((s >> 3) ^ (n & 7)) << 3) | (s & 7))];
    }
    u16* dst = vout + ((size_t)bh * 64 + d) * Ln + lc * 64;
    int b0 = cp0 >> 3;
    *(u16x8*)&dst[((b0 ^ (d & 7)) << 3)]       = *(const u16x8*)&buf[0];
    *(u16x8*)&dst[(((b0 + 1) ^ (d & 7)) << 3)] = *(const u16x8*)&buf[8];
}

// ---------------------------------------------------------------------------
// Split-KV MFMA flash attention (r13 LDS version).  1D XCD-swizzled grid of
// 1024 blocks: block = (qb, bh, kvh) = 128 q-rows x 1024 keys (16 chunks).
// K/V staged global->LDS (gload16), double-buffered, one barrier per chunk.
// Swapped QK^T, in-register P, fixed-max softmax, no denominator.  Writes
// bf16 PARTIAL O to part[(kvh*32+bh)][di][q][c16]; halves add in combine.
// ---------------------------------------------------------------------------
__global__ __launch_bounds__(256, 4)
void attn_mfma(const u16* __restrict__ qt, const u16* __restrict__ kt,
               const u16* __restrict__ vT, u16* __restrict__ part)
{
    __shared__ u16 smem[4 * 4096];   // kbuf0 | kbuf1 | vbuf0 | vbuf1 (8KB each)

    const int t = threadIdx.x;
    const int lane = t & 63, w = t >> 6;
    const int g = lane >> 4, c = lane & 15;
    // XCD-swizzled decode: group gidx = kvh*32+bh stays on XCD (gidx&7)
    const int id  = blockIdx.x;
    const int qb  = (id >> 3) & 15;
    const int gidx = (id & 7) | ((id >> 7) << 3);   // 0..63
    const int bh  = gidx & 31;
    const int kvh = gidx >> 5;
    const int q0  = qb * 128;
    const u16* Q = qt + (size_t)bh * Ln * 64;
    const u16* K = kt + (size_t)bh * Ln * 64 + (size_t)kvh * (1024 * 64);
    const u16* V = vT + (size_t)bh * 64 * (size_t)Ln + kvh * 1024;

    // Q fragments (2 row-frags x 2 k-halves) in registers for the whole sweep
    bf16x8 qa[2][2];
#pragma unroll
    for (int mi = 0; mi < 2; ++mi)
#pragma unroll
        for (int kk = 0; kk < 2; ++kk) {
            int row = q0 + w * 32 + mi * 16 + c;
            qa[mi][kk] = *(const bf16x8*)(Q + (size_t)row * 64 +
                                          (((kk * 4 + g) ^ (c & 7)) << 3));
        }

    f32x4 o[2][4];
    const f32x4 z4 = {0.f, 0.f, 0.f, 0.f};
#pragma unroll
    for (int mi = 0; mi < 2; ++mi)
#pragma unroll
        for (int di = 0; di < 4; ++di) o[mi][di] = z4;

    // hoisted fragment base BYTE offsets within one 8KB buffer:
    // row r=c (128B rows), 16B block b at byte ((b ^ (c&7)) << 4)
    const int fb0 = c * 128 + (((0 + g) ^ (c & 7)) << 4);   // kk=0: b = g
    const int fb1 = c * 128 + (((4 + g) ^ (c & 7)) << 4);   // kk=1: b = 4+g

    char* sb = (char*)smem;
    const int cr = t >> 3, cb = t & 7;
    const u16* kp = K + (size_t)cr * 64 + cb * 8;
    const u16* vp = V + (size_t)cr * Ln + cb * 8;

    // prologue: stage chunk 0 into buffer 0
    gload16(kp,            sb + t * 16);
    gload16(kp + 2048,     sb + 4096 + t * 16);
    gload16(vp,            sb + 16384 + t * 16);
    gload16(vp + 32 * Ln,  sb + 16384 + 4096 + t * 16);

    constexpr int NC = 1024 / 64;   // 16 chunks per half
    for (int ch = 0; ch < NC; ++ch) {
        __syncthreads();   // staged chunk ch visible (drains gloads), prior reads done
        if (ch + 1 < NC) { // issue next-chunk staging; lands by next barrier
            const u16* kn = kp + (ch + 1) * 4096;
            const u16* vn = vp + (ch + 1) * 64;
            char* db = sb + (((ch + 1) & 1) << 13);
            gload16(kn,           db + t * 16);
            gload16(kn + 2048,    db + 4096 + t * 16);
            gload16(vn,           db + 16384 + t * 16);
            gload16(vn + 32 * Ln, db + 16384 + 4096 + t * 16);
        }
        const char* kbb = sb + ((ch & 1) << 13);
        const char* vbb = kbb + 16384;

        // ---- QK^T swapped: sf[mi][ni][j] = S[k=16ni+4g+j][q=16mi+c] ----
        f32x4 sf[2][4];
#pragma unroll
        for (int mi = 0; mi < 2; ++mi)
#pragma unroll
            for (int ni = 0; ni < 4; ++ni) sf[mi][ni] = z4;
        __builtin_amdgcn_s_setprio(1);
#pragma unroll
        for (int kk = 0; kk < 2; ++kk) {
            const int fb = kk ? fb1 : fb0;
            bf16x8 kb[4];
#pragma unroll
            for (int ni = 0; ni < 4; ++ni)
                kb[ni] = *(const bf16x8*)(kbb + fb + ni * 2048);
#pragma unroll
            for (int mi = 0; mi < 2; ++mi)
#pragma unroll
                for (int ni = 0; ni < 4; ++ni)
                    sf[mi][ni] = __builtin_amdgcn_mfma_f32_16x16x32_bf16(
                        kb[ni], qa[mi][kk], sf[mi][ni], 0, 0, 0);
        }
        __builtin_amdgcn_s_setprio(0);

        // ---- softmax numerator (fixed max 0) + P frags in registers ----
        bf16x8 paf[2][2];
#pragma unroll
        for (int mi = 0; mi < 2; ++mi) {
            float ex[4][4];
#pragma unroll
            for (int ni = 0; ni < 4; ++ni)
#pragma unroll
                for (int j = 0; j < 4; ++j)
                    ex[ni][j] = exp2_fast(sf[mi][ni][j]);
            u32x4 p0 = { pkbf(ex[0][0], ex[0][1]), pkbf(ex[0][2], ex[0][3]),
                         pkbf(ex[1][0], ex[1][1]), pkbf(ex[1][2], ex[1][3]) };
            u32x4 p1 = { pkbf(ex[2][0], ex[2][1]), pkbf(ex[2][2], ex[2][3]),
                         pkbf(ex[3][0], ex[3][1]), pkbf(ex[3][2], ex[3][3]) };
            paf[mi][0] = __builtin_bit_cast(bf16x8, p0);
            paf[mi][1] = __builtin_bit_cast(bf16x8, p1);
        }

        // ---- PV (16 MFMA): O[q][d] += P[q][k] V[k][d] ----
        __builtin_amdgcn_s_setprio(1);
#pragma unroll
        for (int kk = 0; kk < 2; ++kk) {
            const int fb = kk ? fb1 : fb0;
#pragma unroll
            for (int di = 0; di < 4; ++di) {
                bf16x8 vb = *(const bf16x8*)(vbb + fb + di * 2048);
#pragma unroll
                for (int mi = 0; mi < 2; ++mi)
                    o[mi][di] = __builtin_amdgcn_mfma_f32_16x16x32_bf16(
                        paf[mi][kk], vb, o[mi][di], 0, 0, 0);
            }
        }
        __builtin_amdgcn_s_setprio(0);
    }

    // ---- epilogue: store bf16 partial O ----
    u16* P = part + (size_t)(kvh * 32 + bh) * (4 * 2048 * 16);
#pragma unroll
    for (int mi = 0; mi < 2; ++mi)
#pragma unroll
        for (int j = 0; j < 4; ++j) {
            int row = q0 + w * 32 + mi * 16 + g * 4 + j;
#pragma unroll
            for (int di = 0; di < 4; ++di)
                P[(di * 2048 + row) * 16 + c] = f2bf(o[mi][di][j]);
        }
}

// ---------------------------------------------------------------------------
// Combine the two KV-half partials, Lorentz-normalize per head row, write
// bf16 cat (slot order + swizzle).  16-lane group per (bh,q) row.
// ---------------------------------------------------------------------------
__global__ __launch_bounds__(256)
void attn_combine(const u16* __restrict__ part, u16* __restrict__ cat)
{
    const int grp = blockIdx.x * 16 + (threadIdx.x >> 4);  // row id in [0,65536)
    const int c = threadIdx.x & 15;
    const int bh = grp >> 11, q = grp & 2047;
    const u16* P0 = part + (size_t)bh * (4 * 2048 * 16);
    const u16* P1 = part + (size_t)(32 + bh) * (4 * 2048 * 16);
    float mu[4];
#pragma unroll
    for (int di = 0; di < 4; ++di) {
        int idx = (di * 2048 + q) * 16 + c;
        mu[di] = bf2f(P0[idx]) + bf2f(P1[idx]);
    }
    float loc = mu[0]*mu[0] + mu[1]*mu[1] + mu[2]*mu[2] + mu[3]*mu[3];
    if (c == 0) loc -= 2.f * mu[0] * mu[0];   // Lorentz inner <o,o>
    loc = red16_add(loc);
    float rn = rsqrtf(fmaxf(fabsf(loc), 1e-6f));
    const int b = bh >> 4, h = bh & 15;
    u16* dst = cat + ((size_t)b * Ln + q) * Dn + h * 64;
    u16x4 pkv = { f2bf(mu[0] * rn), f2bf(mu[1] * rn),
                  f2bf(mu[2] * rn), f2bf(mu[3] * rn) };
    *(u16x4*)&dst[(4 * c) ^ ((q & 7) << 3)] = pkv;
}

// ---------------------------------------------------------------------------
// Output GEMM: out[4096][1024] = cat @ wo^T + b_O (f32 out).
// 64x128 tile, BK=64, double-buffered (48 KB), XCD-swizzled 512 blocks.
// (round-10 proven structure)
// ---------------------------------------------------------------------------
__global__ __launch_bounds__(256)
void gemm_o(const u16* __restrict__ A, const u16* __restrict__ B,
            const float* __restrict__ bias, float* __restrict__ C)
{
    __shared__ u16 As[2][64 * 64];
    __shared__ u16 Bs[2][128 * 64];
    const int t = threadIdx.x;
    const int lane = t & 63, w = t >> 6;
    const int g = lane >> 4, c = lane & 15;
    const int wr = w >> 1, wc = w & 1;
    // XCD decode: y = (id&7)*8 + ((id>>3)&7) in [0,64), x = id>>6 in [0,8)
    const int id = blockIdx.x;
    const int bm = ((id & 7) * 8 + ((id >> 3) & 7)) * 64;
    const int bn = (id >> 6) * 128;

    f32x4 acc[2][4];
    const f32x4 z4 = {0.f, 0.f, 0.f, 0.f};
#pragma unroll
    for (int i = 0; i < 2; ++i)
#pragma unroll
        for (int j = 0; j < 4; ++j) acc[i][j] = z4;

    const int sr = t >> 3, sb2 = (t & 7) * 8;
    const u16* Ap = A + (size_t)(bm + sr) * Dn + sb2;
    const u16* Bp = B + (size_t)(bn + sr) * Dn + sb2;

    auto stage = [&](int buf, int k0) {
        gload16(Ap + k0,            &As[buf][t * 8]);
        gload16(Ap + 32 * Dn + k0,  &As[buf][(256 + t) * 8]);
        gload16(Bp + k0,            &Bs[buf][t * 8]);
        gload16(Bp + 32 * Dn + k0,  &Bs[buf][(256 + t) * 8]);
        gload16(Bp + 64 * Dn + k0,  &Bs[buf][(512 + t) * 8]);
        gload16(Bp + 96 * Dn + k0,  &Bs[buf][(768 + t) * 8]);
    };

    stage(0, 0);
    for (int ki = 0; ki < 16; ++ki) {
        __syncthreads();
        if (ki + 1 < 16) stage((ki + 1) & 1, (ki + 1) * 64);
        const u16* as = As[ki & 1];
        const u16* bs = Bs[ki & 1];
#pragma unroll
        for (int kk = 0; kk < 2; ++kk) {
            const int so = ((kk * 4 + g) ^ (c & 7)) << 3;
            bf16x8 a[2], b[4];
#pragma unroll
            for (int mi = 0; mi < 2; ++mi)
                a[mi] = *(const bf16x8*)&as[(wr * 32 + mi * 16 + c) * 64 + so];
#pragma unroll
            for (int ni = 0; ni < 4; ++ni)
                b[ni] = *(const bf16x8*)&bs[(wc * 64 + ni * 16 + c) * 64 + so];
            __builtin_amdgcn_s_setprio(1);
#pragma unroll
            for (int mi = 0; mi < 2; ++mi)
#pragma unroll
                for (int ni = 0; ni < 4; ++ni)
                    acc[mi][ni] = __builtin_amdgcn_mfma_f32_16x16x32_bf16(
                        a[mi], b[ni], acc[mi][ni], 0, 0, 0);
            __builtin_amdgcn_s_setprio(0);
        }
    }

#pragma unroll
    for (int mi = 0; mi < 2; ++mi)
#pragma unroll
        for (int j = 0; j < 4; ++j) {
            size_t row = bm + wr * 32 + mi * 16 + g * 4 + j;
#pragma unroll
            for (int ni = 0; ni < 4; ++ni) {
                int col = bn + wc * 64 + ni * 16 + c;
                C[row * Dn + col] = acc[mi][ni][j] + bias[col];
            }
        }
}

// ---------------------------------------------------------------------------
// Full-row (D=1024) Lorentz projection on f32 output rows.
// ---------------------------------------------------------------------------
__global__ __launch_bounds__(256)
void lorentz_row_full(float* __restrict__ z)
{
    __shared__ float red[4];
    const int t = threadIdx.x;
    const size_t base = (size_t)blockIdx.x * Dn;
    float4 v = *(const float4*)&z[base + t * 4];
    if (t == 0) v.x = 0.f;
    float ssq = v.x * v.x + v.y * v.y + v.z * v.z + v.w * v.w;
#pragma unroll
    for (int off = 32; off; off >>= 1) ssq += __shfl_xor(ssq, off);
    if ((t & 63) == 0) red[t >> 6] = ssq;
    __syncthreads();
    if (t == 0) z[base] = sqrtf(1.0f + red[0] + red[1] + red[2] + red[3]);
}

// ---------------------------------------------------------------------------
extern "C" void kernel_launch(void* const* d_in, const int* in_sizes, int n_in,
                              void* d_out, int out_size, void* d_ws, size_t ws_size,
                              hipStream_t stream)
{
    const float* query = (const float*)d_in[0];
    const float* key_  = (const float*)d_in[1];
    const float* value = (const float*)d_in[2];
    const float* W_Q   = (const float*)d_in[3];
    const float* b_Q   = (const float*)d_in[4];
    const float* W_K   = (const float*)d_in[5];
    const float* b_K   = (const float*)d_in[6];
    const float* W_V   = (const float*)d_in[7];
    const float* b_V   = (const float*)d_in[8];
    const float* W_O   = (const float*)d_in[9];
    const float* b_O   = (const float*)d_in[10];

    // ws layout (u16 elems; 64 MiB budget).  part aliases wq/wk/wv/v_ln,
    // all of which are dead before attn_mfma runs.
    const size_t MD = (size_t)Mn * Dn;   // 4M elems (8 MiB)
    const size_t DD = (size_t)Dn * Dn;   // 1M elems (2 MiB)
    u16* xq   = (u16*)d_ws;              //  0M..4M   swz input q
    u16* xk   = xq + MD;                 //  4M..8M   swz input k
    u16* xv   = xk + MD;                 //  8M..12M  swz input v
    u16* wo   = xv + MD;                 // 12M..13M  W_O (swz + col perm)
    u16* q_t  = wo + DD;                 // 13M..17M  [b][h][l][64slots]
    u16* k_t  = q_t + MD;                // 17M..21M
    u16* wq   = k_t + MD;                // 21M..22M
    u16* wk   = wq + DD;                 // 22M..23M
    u16* wv   = wk + DD;                 // 23M..24M
    u16* v_ln = wv + DD;                 // 24M..28M  V projection
    u16* part = wq;                      // 21M..29M  bf16 partials (16 MiB)
    u16* v_T  = xv;                      // alias: xv dead after gemm_qkv
    u16* cat  = xk;                      // alias: xk dead after gemm_qkv

    dim3 ci(Mn * Dn / 1024, 3);                // (4096, 3)
    cvt_in3<<<ci, 256, 0, stream>>>(query, key_, value, xq, xk, xv);
    dim3 cw(Dn * Dn / 1024, 4);                // (1024, 4)
    cvt_w<<<cw, 256, 0, stream>>>(W_Q, W_K, W_V, W_O, wq, wk, wv, wo);

    gemm_qkv<<<768, 256, 0, stream>>>(xq, xk, xv, wq, wk, wv,
                                      b_Q, b_K, b_V, q_t, k_t, v_ln);

    dim3 tg(32, Ln / 64);                      // (32, 32)
    transpose_v<<<tg, 256, 0, stream>>>(v_ln, v_T);

    attn_mfma<<<1024, 256, 0, stream>>>(q_t, k_t, v_T, part);  // XCD-swizzled 1D

    attn_combine<<<4096, 256, 0, stream>>>(part, cat);

    gemm_o<<<512, 256, 0, stream>>>(cat, wo, b_O, (float*)d_out);
    lorentz_row_full<<<Mn, 256, 0, stream>>>((float*)d_out);
}

// Round 17
// 124.126 us; speedup vs baseline: 1.1058x; 1.0414x over previous
//
#include <hip/hip_runtime.h>
#include <math.h>

namespace {
constexpr int Ln = 2048;
constexpr int Dn = 1024;
constexpr int Mn = 4096;   // B*L
constexpr float QSCALE = 0.25f * 1.44269504088896340736f; // 2/sqrt(64) * log2(e)
}

typedef unsigned short u16;
typedef unsigned int u32;
typedef __attribute__((ext_vector_type(4))) float f32x4;
typedef __attribute__((ext_vector_type(8))) __bf16 bf16x8;
typedef __attribute__((ext_vector_type(4))) unsigned short u16x4;
typedef __attribute__((ext_vector_type(8))) unsigned short u16x8;
typedef __attribute__((ext_vector_type(4))) unsigned int u32x4;

// ============================================================================
// LAYOUT CONVENTIONS (write-side must match read-side):
// * bf16 matrices are stored in global PRE-SWIZZLED: within each 64-element
//   (128B) k-slice of a row l, the 16B block b sits at position b ^ (l&7).
//   LDS tiles staged by global_load_lds inherit this layout; fragment
//   readers apply the same XOR with the local row (tiles 8-row aligned).
// * Q/K projections store head features in SLOT order s = 4*(d&15) + (d>>4).
//   Q and K share the permutation => dot products unchanged.  V stored same
//   way; transpose_v un-permutes.  cat uses the same slot order per head,
//   compensated by permuting W_O's input columns.
// * v_T ([bh][d][2048]) position y within each 64-chunk holds physical key
//   nu(y) = (y>>5)*32 + ((y>>2)&1)*16 + ((y>>3)&3)*4 + (y&3), so the PV
//   A-fragment equals exp2(sf[..]) of the SAME lane after swapped QK^T.
// * Fixed-max softmax (hyperboloid: scores<=0) => split-KV partials combine
//   by pure addition; Lorentz normalize is scale-invariant => no denominator.
// * gemm_qkv is the r10 LDS-dbuf version: r13/r16's barrier-free variant was
//   4.5us faster in isolation but cost ~9us system-wide (L2 pollution from
//   ~770MB of per-lane fragment reads + ragged tail delaying attn).  r10's
//   config is the best measured total (124.4us).
// ============================================================================

__device__ __forceinline__ u16 f2bf(float f) {
    union { float f; unsigned u; } cv; cv.f = f;
    unsigned u = cv.u + 0x7fffu + ((cv.u >> 16) & 1u);
    return (u16)(u >> 16);
}
__device__ __forceinline__ float bf2f(u16 h) {
    union { unsigned u; float f; } cv; cv.u = ((unsigned)h) << 16;
    return cv.f;
}

__device__ __forceinline__ u32 pkbf(float a, float b) {
    union { __bf16 h[2]; u32 u; } cv;
    cv.h[0] = (__bf16)a; cv.h[1] = (__bf16)b;
    return cv.u;
}

// native exp2: inputs here are in [-50, 0.5] -> normal results.
#if __has_builtin(__builtin_amdgcn_exp2f)
__device__ __forceinline__ float exp2_fast(float x) {
    return __builtin_amdgcn_exp2f(x);
}
#else
__device__ __forceinline__ float exp2_fast(float x) {
    float r;
    asm("v_exp_f32 %0, %1" : "=v"(r) : "v"(x));
    return r;
}
#endif

// DPP cross-lane (16-lane row) sum — VALU pipe, no LDS
template <int CTRL>
__device__ __forceinline__ float dppf(float x) {
    return __int_as_float(__builtin_amdgcn_update_dpp(
        0, __float_as_int(x), CTRL, 0xf, 0xf, true));
}
__device__ __forceinline__ float red16_add(float x) {
    x += dppf<0xB1>(x);    // quad_perm(1,0,3,2)
    x += dppf<0x4E>(x);    // quad_perm(2,3,0,1)
    x += dppf<0x141>(x);   // row_half_mirror
    x += dppf<0x140>(x);   // row_mirror
    return x;
}

__device__ __forceinline__ void gload16(const void* g, void* l) {
    __builtin_amdgcn_global_load_lds(
        (const __attribute__((address_space(1))) unsigned int*)g,
        (__attribute__((address_space(3))) unsigned int*)l, 16, 0, 0);
}

// ---------------------------------------------------------------------------
// f32 -> bf16 convert of the 3 inputs, swizzled global layout (rows of 1024).
// ---------------------------------------------------------------------------
__global__ __launch_bounds__(256)
void cvt_in3(const float* __restrict__ i0, const float* __restrict__ i1,
             const float* __restrict__ i2,
             u16* __restrict__ o0, u16* __restrict__ o1, u16* __restrict__ o2)
{
    const int z = blockIdx.y;
    const float* in = z == 0 ? i0 : (z == 1 ? i1 : i2);
    u16* out       = z == 0 ? o0 : (z == 1 ? o1 : o2);
    int i = blockIdx.x * 256 + threadIdx.x;        // group of 4 elements
    f32x4 v = ((const f32x4*)in)[i];
    u16x4 o;
#pragma unroll
    for (int j = 0; j < 4; ++j) o[j] = f2bf(v[j]);
    int l = i >> 8;                // row
    int e = (i & 255) * 4;         // element within row
    int idx = l * 1024 + (e & ~63) + (((((e >> 3) & 7) ^ (l & 7))) << 3) + (e & 7);
    *(u16x4*)&out[idx] = o;
}

// ---------------------------------------------------------------------------
// Weights cvt: wq/wk/wv plain swizzle; wo (z==3) also permutes input columns
// to cat's per-head slot order.
// ---------------------------------------------------------------------------
__global__ __launch_bounds__(256)
void cvt_w(const float* __restrict__ w0, const float* __restrict__ w1,
           const float* __restrict__ w2, const float* __restrict__ w3,
           u16* __restrict__ q0, u16* __restrict__ q1,
           u16* __restrict__ q2, u16* __restrict__ q3)
{
    const int z = blockIdx.y;
    int i = blockIdx.x * 256 + threadIdx.x;
    if (z < 3) {
        const float* in = z == 0 ? w0 : (z == 1 ? w1 : w2);
        u16* out       = z == 0 ? q0 : (z == 1 ? q1 : q2);
        f32x4 v = ((const f32x4*)in)[i];
        u16x4 o;
#pragma unroll
        for (int j = 0; j < 4; ++j) o[j] = f2bf(v[j]);
        int l = i >> 8;
        int e = (i & 255) * 4;
        int idx = l * 1024 + (e & ~63) + (((((e >> 3) & 7) ^ (l & 7))) << 3) + (e & 7);
        *(u16x4*)&out[idx] = o;
    } else {
        int o  = i >> 8;             // output row of W_O (natural)
        int s0 = (i & 255) * 4;      // out column-slot base
        int h = s0 >> 6, sl = s0 & 63, a = sl >> 2;
        const float* src = w3 + (size_t)o * 1024 + h * 64;
        // slot s0+j holds input feature h*64 + j*16 + a
        u16x4 ov = { f2bf(src[a]), f2bf(src[16 + a]),
                     f2bf(src[32 + a]), f2bf(src[48 + a]) };
        int idx = o * 1024 + h * 64 + (((sl >> 3) ^ (o & 7)) << 3) + (sl & 7);
        *(u16x4*)&q3[idx] = ov;
    }
}

// ---------------------------------------------------------------------------
// Q/K/V projection GEMM + fused per-head Lorentz projection (r10 version).
// 64x128 tile, BK=64, DOUBLE-BUFFERED LDS (48 KB -> 3 blocks/CU), single
// barrier per k-iter.  1536 blocks, XCD-swizzled: XCD k owns y-panels
// [8k,8k+8) for all x,z.  Output bf16 [b][h][l][64slots].
// ---------------------------------------------------------------------------
__global__ __launch_bounds__(256)
void gemm_qkv(const u16* __restrict__ xq, const u16* __restrict__ xk,
              const u16* __restrict__ xv, const u16* __restrict__ wq,
              const u16* __restrict__ wk, const u16* __restrict__ wv,
              const float* __restrict__ bq, const float* __restrict__ bk,
              const float* __restrict__ bv,
              u16* __restrict__ oq, u16* __restrict__ ok, u16* __restrict__ ov)
{
    __shared__ u16 As[2][64 * 64];
    __shared__ u16 Bs[2][128 * 64];
    const int t = threadIdx.x;
    const int lane = t & 63, w = t >> 6;
    const int g = lane >> 4, c = lane & 15;
    const int wr = w >> 1, wc = w & 1;
    // XCD decode: y = (id&7)*8 + ((id>>3)&7), x = (id>>6)&7, z = id>>9
    const int id = blockIdx.x;
    const int bm = ((id & 7) * 8 + ((id >> 3) & 7)) * 64;
    const int bn = ((id >> 6) & 7) * 128;
    const int z  = id >> 9;

    const u16* A = z == 0 ? xq : (z == 1 ? xk : xv);
    const u16* W = z == 0 ? wq : (z == 1 ? wk : wv);
    const float* bias = z == 0 ? bq : (z == 1 ? bk : bv);
    u16* Ct = z == 0 ? oq : (z == 1 ? ok : ov);
    const float scale = z == 0 ? QSCALE : 1.f;
    const float tsign = z == 0 ? -1.f : 1.f;

    f32x4 acc[2][4];
    const f32x4 z4 = {0.f, 0.f, 0.f, 0.f};
#pragma unroll
    for (int i = 0; i < 2; ++i)
#pragma unroll
        for (int j = 0; j < 4; ++j) acc[i][j] = z4;

    const int sr = t >> 3, sb2 = (t & 7) * 8;   // staging row / elem offset
    const u16* Ap = A + (size_t)(bm + sr) * Dn + sb2;
    const u16* Wp = W + (size_t)(bn + sr) * Dn + sb2;

    auto stage = [&](int buf, int k0) {
        gload16(Ap + k0,            &As[buf][t * 8]);
        gload16(Ap + 32 * Dn + k0,  &As[buf][(256 + t) * 8]);
        gload16(Wp + k0,            &Bs[buf][t * 8]);
        gload16(Wp + 32 * Dn + k0,  &Bs[buf][(256 + t) * 8]);
        gload16(Wp + 64 * Dn + k0,  &Bs[buf][(512 + t) * 8]);
        gload16(Wp + 96 * Dn + k0,  &Bs[buf][(768 + t) * 8]);
    };

    stage(0, 0);                               // prologue
    for (int ki = 0; ki < 16; ++ki) {
        __syncthreads();                       // tile ki staged; prior reads done
        if (ki + 1 < 16) stage((ki + 1) & 1, (ki + 1) * 64);
        const u16* as = As[ki & 1];
        const u16* bs = Bs[ki & 1];
#pragma unroll
        for (int kk = 0; kk < 2; ++kk) {
            const int so = ((kk * 4 + g) ^ (c & 7)) << 3;
            bf16x8 a[2], b[4];
#pragma unroll
            for (int mi = 0; mi < 2; ++mi)
                a[mi] = *(const bf16x8*)&as[(wr * 32 + mi * 16 + c) * 64 + so];
#pragma unroll
            for (int ni = 0; ni < 4; ++ni)
                b[ni] = *(const bf16x8*)&bs[(wc * 64 + ni * 16 + c) * 64 + so];
            __builtin_amdgcn_s_setprio(1);
#pragma unroll
            for (int mi = 0; mi < 2; ++mi)
#pragma unroll
                for (int ni = 0; ni < 4; ++ni)
                    acc[mi][ni] = __builtin_amdgcn_mfma_f32_16x16x32_bf16(
                        a[mi], b[ni], acc[mi][ni], 0, 0, 0);
            __builtin_amdgcn_s_setprio(0);
        }
    }

    // fused per-head Lorentz projection epilogue
    const int hcb = bn + wc * 64;
    const int h = hcb >> 6;
#pragma unroll
    for (int mi = 0; mi < 2; ++mi)
#pragma unroll
        for (int j = 0; j < 4; ++j) {
            int ll = bm + wr * 32 + mi * 16 + g * 4 + j;
            float zv[4];
#pragma unroll
            for (int ni = 0; ni < 4; ++ni)
                zv[ni] = acc[mi][ni][j] + bias[hcb + ni * 16 + c];
            float loc = zv[0]*zv[0] + zv[1]*zv[1] + zv[2]*zv[2] + zv[3]*zv[3];
            if (c == 0) loc -= zv[0] * zv[0];     // z0 is DISCARDED (once!)
            loc = red16_add(loc);                 // = sum of space^2
            float tval = sqrtf(1.f + loc);
            float v0 = (c == 0) ? tsign * tval : zv[0];
            int bb = ll >> 11, l2 = ll & 2047;
            u16* dst = Ct + (((size_t)bb * 16 + h) * Ln + l2) * 64;
            u16x4 pkv = { f2bf(v0 * scale), f2bf(zv[1] * scale),
                          f2bf(zv[2] * scale), f2bf(zv[3] * scale) };
            *(u16x4*)&dst[(4 * c) ^ ((ll & 7) << 3)] = pkv;
        }
}

// ---------------------------------------------------------------------------
// V transpose: [bh][l][64 slots,swz] -> v_T [bh][d][2048] where position y
// within each 64-chunk holds key nu(y) (see header), byte-swizzled per (d&7).
// ---------------------------------------------------------------------------
__global__ __launch_bounds__(256)
void transpose_v(const u16* __restrict__ vin, u16* __restrict__ vout)
{
    __shared__ u16 raw[64 * 64];     // straight copy of the swizzled tile
    const int t = threadIdx.x;
    const int bh = blockIdx.x, lc = blockIdx.y;
    const u16* src = vin + ((size_t)bh * Ln + lc * 64) * 64;
#pragma unroll
    for (int p = 0; p < 2; ++p) {
        int ci = p * 256 + t;
        *(u16x8*)&raw[ci * 8] = *(const u16x8*)(src + ci * 8);
    }
    __syncthreads();
    const int d = t >> 2, cp0 = (t & 3) * 16;
    const int s = ((d & 15) << 2) | (d >> 4);   // slot of true feature d
    u16 buf[16];
#pragma unroll
    for (int i = 0; i < 16; ++i) {
        int cp = cp0 + i;
        // physical key for v_T position cp:
        int n = ((cp >> 5) << 5) | (((cp >> 2) & 1) << 4) | (((cp >> 3) & 3) << 2) | (cp & 3);
        buf[i] = raw[n * 64 + ((((s >> 3) ^ (n & 7)) << 3) | (s & 7))];
    }
    u16* dst = vout + ((size_t)bh * 64 + d) * Ln + lc * 64;
    int b0 = cp0 >> 3;
    *(u16x8*)&dst[((b0 ^ (d & 7)) << 3)]       = *(const u16x8*)&buf[0];
    *(u16x8*)&dst[(((b0 + 1) ^ (d & 7)) << 3)] = *(const u16x8*)&buf[8];
}

// ---------------------------------------------------------------------------
// Split-KV MFMA flash attention (LDS version).  1D XCD-swizzled grid of
// 1024 blocks: block = (qb, bh, kvh) = 128 q-rows x 1024 keys (16 chunks).
// K/V staged global->LDS (gload16), double-buffered, one barrier per chunk.
// Swapped QK^T, in-register P, fixed-max softmax, no denominator.  Writes
// bf16 PARTIAL O to part[(kvh*32+bh)][di][q][c16]; halves add in combine.
// ---------------------------------------------------------------------------
__global__ __launch_bounds__(256, 4)
void attn_mfma(const u16* __restrict__ qt, const u16* __restrict__ kt,
               const u16* __restrict__ vT, u16* __restrict__ part)
{
    __shared__ u16 smem[4 * 4096];   // kbuf0 | kbuf1 | vbuf0 | vbuf1 (8KB each)

    const int t = threadIdx.x;
    const int lane = t & 63, w = t >> 6;
    const int g = lane >> 4, c = lane & 15;
    // XCD-swizzled decode: group gidx = kvh*32+bh stays on XCD (gidx&7)
    const int id  = blockIdx.x;
    const int qb  = (id >> 3) & 15;
    const int gidx = (id & 7) | ((id >> 7) << 3);   // 0..63
    const int bh  = gidx & 31;
    const int kvh = gidx >> 5;
    const int q0  = qb * 128;
    const u16* Q = qt + (size_t)bh * Ln * 64;
    const u16* K = kt + (size_t)bh * Ln * 64 + (size_t)kvh * (1024 * 64);
    const u16* V = vT + (size_t)bh * 64 * (size_t)Ln + kvh * 1024;

    // Q fragments (2 row-frags x 2 k-halves) in registers for the whole sweep
    bf16x8 qa[2][2];
#pragma unroll
    for (int mi = 0; mi < 2; ++mi)
#pragma unroll
        for (int kk = 0; kk < 2; ++kk) {
            int row = q0 + w * 32 + mi * 16 + c;
            qa[mi][kk] = *(const bf16x8*)(Q + (size_t)row * 64 +
                                          (((kk * 4 + g) ^ (c & 7)) << 3));
        }

    f32x4 o[2][4];
    const f32x4 z4 = {0.f, 0.f, 0.f, 0.f};
#pragma unroll
    for (int mi = 0; mi < 2; ++mi)
#pragma unroll
        for (int di = 0; di < 4; ++di) o[mi][di] = z4;

    // hoisted fragment base BYTE offsets within one 8KB buffer:
    // row r=c (128B rows), 16B block b at byte ((b ^ (c&7)) << 4)
    const int fb0 = c * 128 + (((0 + g) ^ (c & 7)) << 4);   // kk=0: b = g
    const int fb1 = c * 128 + (((4 + g) ^ (c & 7)) << 4);   // kk=1: b = 4+g

    char* sb = (char*)smem;
    const int cr = t >> 3, cb = t & 7;
    const u16* kp = K + (size_t)cr * 64 + cb * 8;
    const u16* vp = V + (size_t)cr * Ln + cb * 8;

    // prologue: stage chunk 0 into buffer 0
    gload16(kp,            sb + t * 16);
    gload16(kp + 2048,     sb + 4096 + t * 16);
    gload16(vp,            sb + 16384 + t * 16);
    gload16(vp + 32 * Ln,  sb + 16384 + 4096 + t * 16);

    constexpr int NC = 1024 / 64;   // 16 chunks per half
    for (int ch = 0; ch < NC; ++ch) {
        __syncthreads();   // staged chunk ch visible (drains gloads), prior reads done
        if (ch + 1 < NC) { // issue next-chunk staging; lands by next barrier
            const u16* kn = kp + (ch + 1) * 4096;
            const u16* vn = vp + (ch + 1) * 64;
            char* db = sb + (((ch + 1) & 1) << 13);
            gload16(kn,           db + t * 16);
            gload16(kn + 2048,    db + 4096 + t * 16);
            gload16(vn,           db + 16384 + t * 16);
            gload16(vn + 32 * Ln, db + 16384 + 4096 + t * 16);
        }
        const char* kbb = sb + ((ch & 1) << 13);
        const char* vbb = kbb + 16384;

        // ---- QK^T swapped: sf[mi][ni][j] = S[k=16ni+4g+j][q=16mi+c] ----
        f32x4 sf[2][4];
#pragma unroll
        for (int mi = 0; mi < 2; ++mi)
#pragma unroll
            for (int ni = 0; ni < 4; ++ni) sf[mi][ni] = z4;
        __builtin_amdgcn_s_setprio(1);
#pragma unroll
        for (int kk = 0; kk < 2; ++kk) {
            const int fb = kk ? fb1 : fb0;
            bf16x8 kb[4];
#pragma unroll
            for (int ni = 0; ni < 4; ++ni)
                kb[ni] = *(const bf16x8*)(kbb + fb + ni * 2048);
#pragma unroll
            for (int mi = 0; mi < 2; ++mi)
#pragma unroll
                for (int ni = 0; ni < 4; ++ni)
                    sf[mi][ni] = __builtin_amdgcn_mfma_f32_16x16x32_bf16(
                        kb[ni], qa[mi][kk], sf[mi][ni], 0, 0, 0);
        }
        __builtin_amdgcn_s_setprio(0);

        // ---- softmax numerator (fixed max 0) + P frags in registers ----
        bf16x8 paf[2][2];
#pragma unroll
        for (int mi = 0; mi < 2; ++mi) {
            float ex[4][4];
#pragma unroll
            for (int ni = 0; ni < 4; ++ni)
#pragma unroll
                for (int j = 0; j < 4; ++j)
                    ex[ni][j] = exp2_fast(sf[mi][ni][j]);
            u32x4 p0 = { pkbf(ex[0][0], ex[0][1]), pkbf(ex[0][2], ex[0][3]),
                         pkbf(ex[1][0], ex[1][1]), pkbf(ex[1][2], ex[1][3]) };
            u32x4 p1 = { pkbf(ex[2][0], ex[2][1]), pkbf(ex[2][2], ex[2][3]),
                         pkbf(ex[3][0], ex[3][1]), pkbf(ex[3][2], ex[3][3]) };
            paf[mi][0] = __builtin_bit_cast(bf16x8, p0);
            paf[mi][1] = __builtin_bit_cast(bf16x8, p1);
        }

        // ---- PV (16 MFMA): O[q][d] += P[q][k] V[k][d] ----
        __builtin_amdgcn_s_setprio(1);
#pragma unroll
        for (int kk = 0; kk < 2; ++kk) {
            const int fb = kk ? fb1 : fb0;
#pragma unroll
            for (int di = 0; di < 4; ++di) {
                bf16x8 vb = *(const bf16x8*)(vbb + fb + di * 2048);
#pragma unroll
                for (int mi = 0; mi < 2; ++mi)
                    o[mi][di] = __builtin_amdgcn_mfma_f32_16x16x32_bf16(
                        paf[mi][kk], vb, o[mi][di], 0, 0, 0);
            }
        }
        __builtin_amdgcn_s_setprio(0);
    }

    // ---- epilogue: store bf16 partial O ----
    u16* P = part + (size_t)(kvh * 32 + bh) * (4 * 2048 * 16);
#pragma unroll
    for (int mi = 0; mi < 2; ++mi)
#pragma unroll
        for (int j = 0; j < 4; ++j) {
            int row = q0 + w * 32 + mi * 16 + g * 4 + j;
#pragma unroll
            for (int di = 0; di < 4; ++di)
                P[(di * 2048 + row) * 16 + c] = f2bf(o[mi][di][j]);
        }
}

// ---------------------------------------------------------------------------
// Combine the two KV-half partials, Lorentz-normalize per head row, write
// bf16 cat (slot order + swizzle).  16-lane group per (bh,q) row.
// ---------------------------------------------------------------------------
__global__ __launch_bounds__(256)
void attn_combine(const u16* __restrict__ part, u16* __restrict__ cat)
{
    const int grp = blockIdx.x * 16 + (threadIdx.x >> 4);  // row id in [0,65536)
    const int c = threadIdx.x & 15;
    const int bh = grp >> 11, q = grp & 2047;
    const u16* P0 = part + (size_t)bh * (4 * 2048 * 16);
    const u16* P1 = part + (size_t)(32 + bh) * (4 * 2048 * 16);
    float mu[4];
#pragma unroll
    for (int di = 0; di < 4; ++di) {
        int idx = (di * 2048 + q) * 16 + c;
        mu[di] = bf2f(P0[idx]) + bf2f(P1[idx]);
    }
    float loc = mu[0]*mu[0] + mu[1]*mu[1] + mu[2]*mu[2] + mu[3]*mu[3];
    if (c == 0) loc -= 2.f * mu[0] * mu[0];   // Lorentz inner <o,o>
    loc = red16_add(loc);
    float rn = rsqrtf(fmaxf(fabsf(loc), 1e-6f));
    const int b = bh >> 4, h = bh & 15;
    u16* dst = cat + ((size_t)b * Ln + q) * Dn + h * 64;
    u16x4 pkv = { f2bf(mu[0] * rn), f2bf(mu[1] * rn),
                  f2bf(mu[2] * rn), f2bf(mu[3] * rn) };
    *(u16x4*)&dst[(4 * c) ^ ((q & 7) << 3)] = pkv;
}

// ---------------------------------------------------------------------------
// Output GEMM: out[4096][1024] = cat @ wo^T + b_O (f32 out).
// 64x128 tile, BK=64, double-buffered (48 KB), XCD-swizzled 512 blocks.
// ---------------------------------------------------------------------------
__global__ __launch_bounds__(256)
void gemm_o(const u16* __restrict__ A, const u16* __restrict__ B,
            const float* __restrict__ bias, float* __restrict__ C)
{
    __shared__ u16 As[2][64 * 64];
    __shared__ u16 Bs[2][128 * 64];
    const int t = threadIdx.x;
    const int lane = t & 63, w = t >> 6;
    const int g = lane >> 4, c = lane & 15;
    const int wr = w >> 1, wc = w & 1;
    // XCD decode: y = (id&7)*8 + ((id>>3)&7) in [0,64), x = id>>6 in [0,8)
    const int id = blockIdx.x;
    const int bm = ((id & 7) * 8 + ((id >> 3) & 7)) * 64;
    const int bn = (id >> 6) * 128;

    f32x4 acc[2][4];
    const f32x4 z4 = {0.f, 0.f, 0.f, 0.f};
#pragma unroll
    for (int i = 0; i < 2; ++i)
#pragma unroll
        for (int j = 0; j < 4; ++j) acc[i][j] = z4;

    const int sr = t >> 3, sb2 = (t & 7) * 8;
    const u16* Ap = A + (size_t)(bm + sr) * Dn + sb2;
    const u16* Bp = B + (size_t)(bn + sr) * Dn + sb2;

    auto stage = [&](int buf, int k0) {
        gload16(Ap + k0,            &As[buf][t * 8]);
        gload16(Ap + 32 * Dn + k0,  &As[buf][(256 + t) * 8]);
        gload16(Bp + k0,            &Bs[buf][t * 8]);
        gload16(Bp + 32 * Dn + k0,  &Bs[buf][(256 + t) * 8]);
        gload16(Bp + 64 * Dn + k0,  &Bs[buf][(512 + t) * 8]);
        gload16(Bp + 96 * Dn + k0,  &Bs[buf][(768 + t) * 8]);
    };

    stage(0, 0);
    for (int ki = 0; ki < 16; ++ki) {
        __syncthreads();
        if (ki + 1 < 16) stage((ki + 1) & 1, (ki + 1) * 64);
        const u16* as = As[ki & 1];
        const u16* bs = Bs[ki & 1];
#pragma unroll
        for (int kk = 0; kk < 2; ++kk) {
            const int so = ((kk * 4 + g) ^ (c & 7)) << 3;
            bf16x8 a[2], b[4];
#pragma unroll
            for (int mi = 0; mi < 2; ++mi)
                a[mi] = *(const bf16x8*)&as[(wr * 32 + mi * 16 + c) * 64 + so];
#pragma unroll
            for (int ni = 0; ni < 4; ++ni)
                b[ni] = *(const bf16x8*)&bs[(wc * 64 + ni * 16 + c) * 64 + so];
            __builtin_amdgcn_s_setprio(1);
#pragma unroll
            for (int mi = 0; mi < 2; ++mi)
#pragma unroll
                for (int ni = 0; ni < 4; ++ni)
                    acc[mi][ni] = __builtin_amdgcn_mfma_f32_16x16x32_bf16(
                        a[mi], b[ni], acc[mi][ni], 0, 0, 0);
            __builtin_amdgcn_s_setprio(0);
        }
    }

#pragma unroll
    for (int mi = 0; mi < 2; ++mi)
#pragma unroll
        for (int j = 0; j < 4; ++j) {
            size_t row = bm + wr * 32 + mi * 16 + g * 4 + j;
#pragma unroll
            for (int ni = 0; ni < 4; ++ni) {
                int col = bn + wc * 64 + ni * 16 + c;
                C[row * Dn + col] = acc[mi][ni][j] + bias[col];
            }
        }
}

// ---------------------------------------------------------------------------
// Full-row (D=1024) Lorentz projection on f32 output rows.
// ---------------------------------------------------------------------------
__global__ __launch_bounds__(256)
void lorentz_row_full(float* __restrict__ z)
{
    __shared__ float red[4];
    const int t = threadIdx.x;
    const size_t base = (size_t)blockIdx.x * Dn;
    float4 v = *(const float4*)&z[base + t * 4];
    if (t == 0) v.x = 0.f;
    float ssq = v.x * v.x + v.y * v.y + v.z * v.z + v.w * v.w;
#pragma unroll
    for (int off = 32; off; off >>= 1) ssq += __shfl_xor(ssq, off);
    if ((t & 63) == 0) red[t >> 6] = ssq;
    __syncthreads();
    if (t == 0) z[base] = sqrtf(1.0f + red[0] + red[1] + red[2] + red[3]);
}

// ---------------------------------------------------------------------------
extern "C" void kernel_launch(void* const* d_in, const int* in_sizes, int n_in,
                              void* d_out, int out_size, void* d_ws, size_t ws_size,
                              hipStream_t stream)
{
    const float* query = (const float*)d_in[0];
    const float* key_  = (const float*)d_in[1];
    const float* value = (const float*)d_in[2];
    const float* W_Q   = (const float*)d_in[3];
    const float* b_Q   = (const float*)d_in[4];
    const float* W_K   = (const float*)d_in[5];
    const float* b_K   = (const float*)d_in[6];
    const float* W_V   = (const float*)d_in[7];
    const float* b_V   = (const float*)d_in[8];
    const float* W_O   = (const float*)d_in[9];
    const float* b_O   = (const float*)d_in[10];

    // ws layout (u16 elems; 64 MiB budget).  part aliases wq/wk/wv/v_ln,
    // all of which are dead before attn_mfma runs.
    const size_t MD = (size_t)Mn * Dn;   // 4M elems (8 MiB)
    const size_t DD = (size_t)Dn * Dn;   // 1M elems (2 MiB)
    u16* xq   = (u16*)d_ws;              //  0M..4M   swz input q
    u16* xk   = xq + MD;                 //  4M..8M   swz input k
    u16* xv   = xk + MD;                 //  8M..12M  swz input v
    u16* wo   = xv + MD;                 // 12M..13M  W_O (swz + col perm)
    u16* q_t  = wo + DD;                 // 13M..17M  [b][h][l][64slots]
    u16* k_t  = q_t + MD;                // 17M..21M
    u16* wq   = k_t + MD;                // 21M..22M
    u16* wk   = wq + DD;                 // 22M..23M
    u16* wv   = wk + DD;                 // 23M..24M
    u16* v_ln = wv + DD;                 // 24M..28M  V projection
    u16* part = wq;                      // 21M..29M  bf16 partials (16 MiB)
    u16* v_T  = xv;                      // alias: xv dead after gemm_qkv
    u16* cat  = xk;                      // alias: xk dead after gemm_qkv

    dim3 ci(Mn * Dn / 1024, 3);                // (4096, 3)
    cvt_in3<<<ci, 256, 0, stream>>>(query, key_, value, xq, xk, xv);
    dim3 cw(Dn * Dn / 1024, 4);                // (1024, 4)
    cvt_w<<<cw, 256, 0, stream>>>(W_Q, W_K, W_V, W_O, wq, wk, wv, wo);

    gemm_qkv<<<1536, 256, 0, stream>>>(xq, xk, xv, wq, wk, wv,
                                       b_Q, b_K, b_V, q_t, k_t, v_ln);

    dim3 tg(32, Ln / 64);                      // (32, 32)
    transpose_v<<<tg, 256, 0, stream>>>(v_ln, v_T);

    attn_mfma<<<1024, 256, 0, stream>>>(q_t, k_t, v_T, part);  // XCD-swizzled 1D

    attn_combine<<<4096, 256, 0, stream>>>(part, cat);

    gemm_o<<<512, 256, 0, stream>>>(cat, wo, b_O, (float*)d_out);
    lorentz_row_full<<<Mn, 256, 0, stream>>>((float*)d_out);
}

// Round 18
// 121.721 us; speedup vs baseline: 1.1276x; 1.0198x over previous
//
#include <hip/hip_runtime.h>
#include <math.h>

namespace {
constexpr int Ln = 2048;
constexpr int Dn = 1024;
constexpr int Mn = 4096;   // B*L
constexpr float QSCALE = 0.25f * 1.44269504088896340736f; // 2/sqrt(64) * log2(e)
}

typedef unsigned short u16;
typedef unsigned int u32;
typedef __attribute__((ext_vector_type(4))) float f32x4;
typedef __attribute__((ext_vector_type(8))) __bf16 bf16x8;
typedef __attribute__((ext_vector_type(4))) unsigned short u16x4;
typedef __attribute__((ext_vector_type(8))) unsigned short u16x8;
typedef __attribute__((ext_vector_type(4))) unsigned int u32x4;

// ============================================================================
// LAYOUT CONVENTIONS (write-side must match read-side):
// * bf16 matrices are stored in global PRE-SWIZZLED: within each 64-element
//   (128B) k-slice of a row l, the 16B block b sits at position b ^ (l&7).
//   LDS tiles staged by global_load_lds inherit this layout; fragment
//   readers apply the same XOR with the local row (tiles 8-row aligned).
// * Q/K projections store head features in SLOT order s = 4*(d&15) + (d>>4).
//   Q and K share the permutation => dot products unchanged.  V stored same
//   way; transpose_v un-permutes.  cat uses the same slot order per head,
//   compensated by permuting W_O's input columns.
// * v_T ([bh][d][2048]) position y within each 64-chunk holds physical key
//   nu(y) = (y>>5)*32 + ((y>>2)&1)*16 + ((y>>3)&3)*4 + (y&3), so the PV
//   A-fragment equals exp2(sf[..]) of the SAME lane after swapped QK^T.
// * Fixed-max softmax (hyperboloid: scores<=0) => split-KV partials combine
//   by pure addition; Lorentz normalize is scale-invariant => no denominator.
// * gemm_qkv is the r10 LDS-dbuf version (best measured system-wide; the
//   barrier-free variant was locally faster but cost ~9us downstream).
// * Full-row Lorentz projection is FUSED into gemm_o: per-row partial sum of
//   squares (excluding col 0) via DPP reduce + atomicAdd into ssq[4096];
//   tiny lorentz_fix kernel writes out[row][0] = sqrt(1+ssq).  ssq is
//   zeroed by cvt_all block (0,0) each launch.
// ============================================================================

__device__ __forceinline__ u16 f2bf(float f) {
    union { float f; unsigned u; } cv; cv.f = f;
    unsigned u = cv.u + 0x7fffu + ((cv.u >> 16) & 1u);
    return (u16)(u >> 16);
}
__device__ __forceinline__ float bf2f(u16 h) {
    union { unsigned u; float f; } cv; cv.u = ((unsigned)h) << 16;
    return cv.f;
}

__device__ __forceinline__ u32 pkbf(float a, float b) {
    union { __bf16 h[2]; u32 u; } cv;
    cv.h[0] = (__bf16)a; cv.h[1] = (__bf16)b;
    return cv.u;
}

// native exp2: inputs here are in [-50, 0.5] -> normal results.
#if __has_builtin(__builtin_amdgcn_exp2f)
__device__ __forceinline__ float exp2_fast(float x) {
    return __builtin_amdgcn_exp2f(x);
}
#else
__device__ __forceinline__ float exp2_fast(float x) {
    float r;
    asm("v_exp_f32 %0, %1" : "=v"(r) : "v"(x));
    return r;
}
#endif

// DPP cross-lane (16-lane row) sum — VALU pipe, no LDS
template <int CTRL>
__device__ __forceinline__ float dppf(float x) {
    return __int_as_float(__builtin_amdgcn_update_dpp(
        0, __float_as_int(x), CTRL, 0xf, 0xf, true));
}
__device__ __forceinline__ float red16_add(float x) {
    x += dppf<0xB1>(x);    // quad_perm(1,0,3,2)
    x += dppf<0x4E>(x);    // quad_perm(2,3,0,1)
    x += dppf<0x141>(x);   // row_half_mirror
    x += dppf<0x140>(x);   // row_mirror
    return x;
}

__device__ __forceinline__ void gload16(const void* g, void* l) {
    __builtin_amdgcn_global_load_lds(
        (const __attribute__((address_space(1))) unsigned int*)g,
        (__attribute__((address_space(3))) unsigned int*)l, 16, 0, 0);
}

// ---------------------------------------------------------------------------
// Combined f32->bf16 convert: z=0..2 inputs (4096 rows), z=3..6 weights
// (1024 rows; z=6 = W_O with column slot-permutation).  Block (0,0) also
// zeroes the per-row ssq accumulator used by the fused output projection.
// ---------------------------------------------------------------------------
__global__ __launch_bounds__(256)
void cvt_all(const float* __restrict__ i0, const float* __restrict__ i1,
             const float* __restrict__ i2, const float* __restrict__ w0,
             const float* __restrict__ w1, const float* __restrict__ w2,
             const float* __restrict__ w3,
             u16* __restrict__ o0, u16* __restrict__ o1, u16* __restrict__ o2,
             u16* __restrict__ q0, u16* __restrict__ q1,
             u16* __restrict__ q2, u16* __restrict__ q3,
             float* __restrict__ ssq)
{
    const int z = blockIdx.y;
    const int bx = blockIdx.x;
    if (z == 0 && bx == 0) {               // zero ssq[4096] every launch
        const f32x4 zz = {0.f, 0.f, 0.f, 0.f};
#pragma unroll
        for (int j = 0; j < 4; ++j)
            ((f32x4*)ssq)[threadIdx.x * 4 + j] = zz;
    }
    if (z < 3) {
        const float* in = z == 0 ? i0 : (z == 1 ? i1 : i2);
        u16* out       = z == 0 ? o0 : (z == 1 ? o1 : o2);
        int i = bx * 256 + threadIdx.x;
        f32x4 v = ((const f32x4*)in)[i];
        u16x4 o;
#pragma unroll
        for (int j = 0; j < 4; ++j) o[j] = f2bf(v[j]);
        int l = i >> 8;
        int e = (i & 255) * 4;
        int idx = l * 1024 + (e & ~63) + (((((e >> 3) & 7) ^ (l & 7))) << 3) + (e & 7);
        *(u16x4*)&out[idx] = o;
    } else if (z < 6) {
        if (bx >= 1024) return;
        const float* in = z == 3 ? w0 : (z == 4 ? w1 : w2);
        u16* out       = z == 3 ? q0 : (z == 4 ? q1 : q2);
        int i = bx * 256 + threadIdx.x;
        f32x4 v = ((const f32x4*)in)[i];
        u16x4 o;
#pragma unroll
        for (int j = 0; j < 4; ++j) o[j] = f2bf(v[j]);
        int l = i >> 8;
        int e = (i & 255) * 4;
        int idx = l * 1024 + (e & ~63) + (((((e >> 3) & 7) ^ (l & 7))) << 3) + (e & 7);
        *(u16x4*)&out[idx] = o;
    } else {
        if (bx >= 1024) return;
        int i = bx * 256 + threadIdx.x;
        int o  = i >> 8;             // output row of W_O (natural)
        int s0 = (i & 255) * 4;      // out column-slot base
        int h = s0 >> 6, sl = s0 & 63, a = sl >> 2;
        const float* src = w3 + (size_t)o * 1024 + h * 64;
        // slot s0+j holds input feature h*64 + j*16 + a
        u16x4 ov = { f2bf(src[a]), f2bf(src[16 + a]),
                     f2bf(src[32 + a]), f2bf(src[48 + a]) };
        int idx = o * 1024 + h * 64 + (((sl >> 3) ^ (o & 7)) << 3) + (sl & 7);
        *(u16x4*)&q3[idx] = ov;
    }
}

// ---------------------------------------------------------------------------
// Q/K/V projection GEMM + fused per-head Lorentz projection (r10 version).
// 64x128 tile, BK=64, DOUBLE-BUFFERED LDS (48 KB -> 3 blocks/CU), single
// barrier per k-iter.  1536 blocks, XCD-swizzled: XCD k owns y-panels
// [8k,8k+8) for all x,z.  Output bf16 [b][h][l][64slots].
// ---------------------------------------------------------------------------
__global__ __launch_bounds__(256)
void gemm_qkv(const u16* __restrict__ xq, const u16* __restrict__ xk,
              const u16* __restrict__ xv, const u16* __restrict__ wq,
              const u16* __restrict__ wk, const u16* __restrict__ wv,
              const float* __restrict__ bq, const float* __restrict__ bk,
              const float* __restrict__ bv,
              u16* __restrict__ oq, u16* __restrict__ ok, u16* __restrict__ ov)
{
    __shared__ u16 As[2][64 * 64];
    __shared__ u16 Bs[2][128 * 64];
    const int t = threadIdx.x;
    const int lane = t & 63, w = t >> 6;
    const int g = lane >> 4, c = lane & 15;
    const int wr = w >> 1, wc = w & 1;
    // XCD decode: y = (id&7)*8 + ((id>>3)&7), x = (id>>6)&7, z = id>>9
    const int id = blockIdx.x;
    const int bm = ((id & 7) * 8 + ((id >> 3) & 7)) * 64;
    const int bn = ((id >> 6) & 7) * 128;
    const int z  = id >> 9;

    const u16* A = z == 0 ? xq : (z == 1 ? xk : xv);
    const u16* W = z == 0 ? wq : (z == 1 ? wk : wv);
    const float* bias = z == 0 ? bq : (z == 1 ? bk : bv);
    u16* Ct = z == 0 ? oq : (z == 1 ? ok : ov);
    const float scale = z == 0 ? QSCALE : 1.f;
    const float tsign = z == 0 ? -1.f : 1.f;

    f32x4 acc[2][4];
    const f32x4 z4 = {0.f, 0.f, 0.f, 0.f};
#pragma unroll
    for (int i = 0; i < 2; ++i)
#pragma unroll
        for (int j = 0; j < 4; ++j) acc[i][j] = z4;

    const int sr = t >> 3, sb2 = (t & 7) * 8;   // staging row / elem offset
    const u16* Ap = A + (size_t)(bm + sr) * Dn + sb2;
    const u16* Wp = W + (size_t)(bn + sr) * Dn + sb2;

    auto stage = [&](int buf, int k0) {
        gload16(Ap + k0,            &As[buf][t * 8]);
        gload16(Ap + 32 * Dn + k0,  &As[buf][(256 + t) * 8]);
        gload16(Wp + k0,            &Bs[buf][t * 8]);
        gload16(Wp + 32 * Dn + k0,  &Bs[buf][(256 + t) * 8]);
        gload16(Wp + 64 * Dn + k0,  &Bs[buf][(512 + t) * 8]);
        gload16(Wp + 96 * Dn + k0,  &Bs[buf][(768 + t) * 8]);
    };

    stage(0, 0);                               // prologue
    for (int ki = 0; ki < 16; ++ki) {
        __syncthreads();                       // tile ki staged; prior reads done
        if (ki + 1 < 16) stage((ki + 1) & 1, (ki + 1) * 64);
        const u16* as = As[ki & 1];
        const u16* bs = Bs[ki & 1];
#pragma unroll
        for (int kk = 0; kk < 2; ++kk) {
            const int so = ((kk * 4 + g) ^ (c & 7)) << 3;
            bf16x8 a[2], b[4];
#pragma unroll
            for (int mi = 0; mi < 2; ++mi)
                a[mi] = *(const bf16x8*)&as[(wr * 32 + mi * 16 + c) * 64 + so];
#pragma unroll
            for (int ni = 0; ni < 4; ++ni)
                b[ni] = *(const bf16x8*)&bs[(wc * 64 + ni * 16 + c) * 64 + so];
            __builtin_amdgcn_s_setprio(1);
#pragma unroll
            for (int mi = 0; mi < 2; ++mi)
#pragma unroll
                for (int ni = 0; ni < 4; ++ni)
                    acc[mi][ni] = __builtin_amdgcn_mfma_f32_16x16x32_bf16(
                        a[mi], b[ni], acc[mi][ni], 0, 0, 0);
            __builtin_amdgcn_s_setprio(0);
        }
    }

    // fused per-head Lorentz projection epilogue
    const int hcb = bn + wc * 64;
    const int h = hcb >> 6;
#pragma unroll
    for (int mi = 0; mi < 2; ++mi)
#pragma unroll
        for (int j = 0; j < 4; ++j) {
            int ll = bm + wr * 32 + mi * 16 + g * 4 + j;
            float zv[4];
#pragma unroll
            for (int ni = 0; ni < 4; ++ni)
                zv[ni] = acc[mi][ni][j] + bias[hcb + ni * 16 + c];
            float loc = zv[0]*zv[0] + zv[1]*zv[1] + zv[2]*zv[2] + zv[3]*zv[3];
            if (c == 0) loc -= zv[0] * zv[0];     // z0 is DISCARDED (once!)
            loc = red16_add(loc);                 // = sum of space^2
            float tval = sqrtf(1.f + loc);
            float v0 = (c == 0) ? tsign * tval : zv[0];
            int bb = ll >> 11, l2 = ll & 2047;
            u16* dst = Ct + (((size_t)bb * 16 + h) * Ln + l2) * 64;
            u16x4 pkv = { f2bf(v0 * scale), f2bf(zv[1] * scale),
                          f2bf(zv[2] * scale), f2bf(zv[3] * scale) };
            *(u16x4*)&dst[(4 * c) ^ ((ll & 7) << 3)] = pkv;
        }
}

// ---------------------------------------------------------------------------
// V transpose: [bh][l][64 slots,swz] -> v_T [bh][d][2048] where position y
// within each 64-chunk holds key nu(y) (see header), byte-swizzled per (d&7).
// ---------------------------------------------------------------------------
__global__ __launch_bounds__(256)
void transpose_v(const u16* __restrict__ vin, u16* __restrict__ vout)
{
    __shared__ u16 raw[64 * 64];     // straight copy of the swizzled tile
    const int t = threadIdx.x;
    const int bh = blockIdx.x, lc = blockIdx.y;
    const u16* src = vin + ((size_t)bh * Ln + lc * 64) * 64;
#pragma unroll
    for (int p = 0; p < 2; ++p) {
        int ci = p * 256 + t;
        *(u16x8*)&raw[ci * 8] = *(const u16x8*)(src + ci * 8);
    }
    __syncthreads();
    const int d = t >> 2, cp0 = (t & 3) * 16;
    const int s = ((d & 15) << 2) | (d >> 4);   // slot of true feature d
    u16 buf[16];
#pragma unroll
    for (int i = 0; i < 16; ++i) {
        int cp = cp0 + i;
        // physical key for v_T position cp:
        int n = ((cp >> 5) << 5) | (((cp >> 2) & 1) << 4) | (((cp >> 3) & 3) << 2) | (cp & 3);
        buf[i] = raw[n * 64 + ((((s >> 3) ^ (n & 7)) << 3) | (s & 7))];
    }
    u16* dst = vout + ((size_t)bh * 64 + d) * Ln + lc * 64;
    int b0 = cp0 >> 3;
    *(u16x8*)&dst[((b0 ^ (d & 7)) << 3)]       = *(const u16x8*)&buf[0];
    *(u16x8*)&dst[(((b0 + 1) ^ (d & 7)) << 3)] = *(const u16x8*)&buf[8];
}

// ---------------------------------------------------------------------------
// Split-KV MFMA flash attention (LDS version).  1D XCD-swizzled grid of
// 1024 blocks: block = (qb, bh, kvh) = 128 q-rows x 1024 keys (16 chunks).
// K/V staged global->LDS (gload16), double-buffered, one barrier per chunk.
// Swapped QK^T, in-register P, fixed-max softmax, no denominator.  Writes
// bf16 PARTIAL O to part[(kvh*32+bh)][di][q][c16]; halves add in combine.
// ---------------------------------------------------------------------------
__global__ __launch_bounds__(256, 4)
void attn_mfma(const u16* __restrict__ qt, const u16* __restrict__ kt,
               const u16* __restrict__ vT, u16* __restrict__ part)
{
    __shared__ u16 smem[4 * 4096];   // kbuf0 | kbuf1 | vbuf0 | vbuf1 (8KB each)

    const int t = threadIdx.x;
    const int lane = t & 63, w = t >> 6;
    const int g = lane >> 4, c = lane & 15;
    // XCD-swizzled decode: group gidx = kvh*32+bh stays on XCD (gidx&7)
    const int id  = blockIdx.x;
    const int qb  = (id >> 3) & 15;
    const int gidx = (id & 7) | ((id >> 7) << 3);   // 0..63
    const int bh  = gidx & 31;
    const int kvh = gidx >> 5;
    const int q0  = qb * 128;
    const u16* Q = qt + (size_t)bh * Ln * 64;
    const u16* K = kt + (size_t)bh * Ln * 64 + (size_t)kvh * (1024 * 64);
    const u16* V = vT + (size_t)bh * 64 * (size_t)Ln + kvh * 1024;

    // Q fragments (2 row-frags x 2 k-halves) in registers for the whole sweep
    bf16x8 qa[2][2];
#pragma unroll
    for (int mi = 0; mi < 2; ++mi)
#pragma unroll
        for (int kk = 0; kk < 2; ++kk) {
            int row = q0 + w * 32 + mi * 16 + c;
            qa[mi][kk] = *(const bf16x8*)(Q + (size_t)row * 64 +
                                          (((kk * 4 + g) ^ (c & 7)) << 3));
        }

    f32x4 o[2][4];
    const f32x4 z4 = {0.f, 0.f, 0.f, 0.f};
#pragma unroll
    for (int mi = 0; mi < 2; ++mi)
#pragma unroll
        for (int di = 0; di < 4; ++di) o[mi][di] = z4;

    // hoisted fragment base BYTE offsets within one 8KB buffer:
    // row r=c (128B rows), 16B block b at byte ((b ^ (c&7)) << 4)
    const int fb0 = c * 128 + (((0 + g) ^ (c & 7)) << 4);   // kk=0: b = g
    const int fb1 = c * 128 + (((4 + g) ^ (c & 7)) << 4);   // kk=1: b = 4+g

    char* sb = (char*)smem;
    const int cr = t >> 3, cb = t & 7;
    const u16* kp = K + (size_t)cr * 64 + cb * 8;
    const u16* vp = V + (size_t)cr * Ln + cb * 8;

    // prologue: stage chunk 0 into buffer 0
    gload16(kp,            sb + t * 16);
    gload16(kp + 2048,     sb + 4096 + t * 16);
    gload16(vp,            sb + 16384 + t * 16);
    gload16(vp + 32 * Ln,  sb + 16384 + 4096 + t * 16);

    constexpr int NC = 1024 / 64;   // 16 chunks per half
    for (int ch = 0; ch < NC; ++ch) {
        __syncthreads();   // staged chunk ch visible (drains gloads), prior reads done
        if (ch + 1 < NC) { // issue next-chunk staging; lands by next barrier
            const u16* kn = kp + (ch + 1) * 4096;
            const u16* vn = vp + (ch + 1) * 64;
            char* db = sb + (((ch + 1) & 1) << 13);
            gload16(kn,           db + t * 16);
            gload16(kn + 2048,    db + 4096 + t * 16);
            gload16(vn,           db + 16384 + t * 16);
            gload16(vn + 32 * Ln, db + 16384 + 4096 + t * 16);
        }
        const char* kbb = sb + ((ch & 1) << 13);
        const char* vbb = kbb + 16384;

        // ---- QK^T swapped: sf[mi][ni][j] = S[k=16ni+4g+j][q=16mi+c] ----
        f32x4 sf[2][4];
#pragma unroll
        for (int mi = 0; mi < 2; ++mi)
#pragma unroll
            for (int ni = 0; ni < 4; ++ni) sf[mi][ni] = z4;
        __builtin_amdgcn_s_setprio(1);
#pragma unroll
        for (int kk = 0; kk < 2; ++kk) {
            const int fb = kk ? fb1 : fb0;
            bf16x8 kb[4];
#pragma unroll
            for (int ni = 0; ni < 4; ++ni)
                kb[ni] = *(const bf16x8*)(kbb + fb + ni * 2048);
#pragma unroll
            for (int mi = 0; mi < 2; ++mi)
#pragma unroll
                for (int ni = 0; ni < 4; ++ni)
                    sf[mi][ni] = __builtin_amdgcn_mfma_f32_16x16x32_bf16(
                        kb[ni], qa[mi][kk], sf[mi][ni], 0, 0, 0);
        }
        __builtin_amdgcn_s_setprio(0);

        // ---- softmax numerator (fixed max 0) + P frags in registers ----
        bf16x8 paf[2][2];
#pragma unroll
        for (int mi = 0; mi < 2; ++mi) {
            float ex[4][4];
#pragma unroll
            for (int ni = 0; ni < 4; ++ni)
#pragma unroll
                for (int j = 0; j < 4; ++j)
                    ex[ni][j] = exp2_fast(sf[mi][ni][j]);
            u32x4 p0 = { pkbf(ex[0][0], ex[0][1]), pkbf(ex[0][2], ex[0][3]),
                         pkbf(ex[1][0], ex[1][1]), pkbf(ex[1][2], ex[1][3]) };
            u32x4 p1 = { pkbf(ex[2][0], ex[2][1]), pkbf(ex[2][2], ex[2][3]),
                         pkbf(ex[3][0], ex[3][1]), pkbf(ex[3][2], ex[3][3]) };
            paf[mi][0] = __builtin_bit_cast(bf16x8, p0);
            paf[mi][1] = __builtin_bit_cast(bf16x8, p1);
        }

        // ---- PV (16 MFMA): O[q][d] += P[q][k] V[k][d] ----
        __builtin_amdgcn_s_setprio(1);
#pragma unroll
        for (int kk = 0; kk < 2; ++kk) {
            const int fb = kk ? fb1 : fb0;
#pragma unroll
            for (int di = 0; di < 4; ++di) {
                bf16x8 vb = *(const bf16x8*)(vbb + fb + di * 2048);
#pragma unroll
                for (int mi = 0; mi < 2; ++mi)
                    o[mi][di] = __builtin_amdgcn_mfma_f32_16x16x32_bf16(
                        paf[mi][kk], vb, o[mi][di], 0, 0, 0);
            }
        }
        __builtin_amdgcn_s_setprio(0);
    }

    // ---- epilogue: store bf16 partial O ----
    u16* P = part + (size_t)(kvh * 32 + bh) * (4 * 2048 * 16);
#pragma unroll
    for (int mi = 0; mi < 2; ++mi)
#pragma unroll
        for (int j = 0; j < 4; ++j) {
            int row = q0 + w * 32 + mi * 16 + g * 4 + j;
#pragma unroll
            for (int di = 0; di < 4; ++di)
                P[(di * 2048 + row) * 16 + c] = f2bf(o[mi][di][j]);
        }
}

// ---------------------------------------------------------------------------
// Combine the two KV-half partials, Lorentz-normalize per head row, write
// bf16 cat (slot order + swizzle).  16-lane group per (bh,q) row.
// ---------------------------------------------------------------------------
__global__ __launch_bounds__(256)
void attn_combine(const u16* __restrict__ part, u16* __restrict__ cat)
{
    const int grp = blockIdx.x * 16 + (threadIdx.x >> 4);  // row id in [0,65536)
    const int c = threadIdx.x & 15;
    const int bh = grp >> 11, q = grp & 2047;
    const u16* P0 = part + (size_t)bh * (4 * 2048 * 16);
    const u16* P1 = part + (size_t)(32 + bh) * (4 * 2048 * 16);
    float mu[4];
#pragma unroll
    for (int di = 0; di < 4; ++di) {
        int idx = (di * 2048 + q) * 16 + c;
        mu[di] = bf2f(P0[idx]) + bf2f(P1[idx]);
    }
    float loc = mu[0]*mu[0] + mu[1]*mu[1] + mu[2]*mu[2] + mu[3]*mu[3];
    if (c == 0) loc -= 2.f * mu[0] * mu[0];   // Lorentz inner <o,o>
    loc = red16_add(loc);
    float rn = rsqrtf(fmaxf(fabsf(loc), 1e-6f));
    const int b = bh >> 4, h = bh & 15;
    u16* dst = cat + ((size_t)b * Ln + q) * Dn + h * 64;
    u16x4 pkv = { f2bf(mu[0] * rn), f2bf(mu[1] * rn),
                  f2bf(mu[2] * rn), f2bf(mu[3] * rn) };
    *(u16x4*)&dst[(4 * c) ^ ((q & 7) << 3)] = pkv;
}

// ---------------------------------------------------------------------------
// Output GEMM: out[4096][1024] = cat @ wo^T + b_O (f32 out) + fused per-row
// partial sum-of-squares (excluding col 0) into ssq via DPP reduce + atomic.
// 64x128 tile, BK=64, double-buffered (48 KB), XCD-swizzled 512 blocks.
// ---------------------------------------------------------------------------
__global__ __launch_bounds__(256)
void gemm_o(const u16* __restrict__ A, const u16* __restrict__ B,
            const float* __restrict__ bias, float* __restrict__ C,
            float* __restrict__ ssq)
{
    __shared__ u16 As[2][64 * 64];
    __shared__ u16 Bs[2][128 * 64];
    const int t = threadIdx.x;
    const int lane = t & 63, w = t >> 6;
    const int g = lane >> 4, c = lane & 15;
    const int wr = w >> 1, wc = w & 1;
    // XCD decode: y = (id&7)*8 + ((id>>3)&7) in [0,64), x = id>>6 in [0,8)
    const int id = blockIdx.x;
    const int bm = ((id & 7) * 8 + ((id >> 3) & 7)) * 64;
    const int bn = (id >> 6) * 128;

    f32x4 acc[2][4];
    const f32x4 z4 = {0.f, 0.f, 0.f, 0.f};
#pragma unroll
    for (int i = 0; i < 2; ++i)
#pragma unroll
        for (int j = 0; j < 4; ++j) acc[i][j] = z4;

    const int sr = t >> 3, sb2 = (t & 7) * 8;
    const u16* Ap = A + (size_t)(bm + sr) * Dn + sb2;
    const u16* Bp = B + (size_t)(bn + sr) * Dn + sb2;

    auto stage = [&](int buf, int k0) {
        gload16(Ap + k0,            &As[buf][t * 8]);
        gload16(Ap + 32 * Dn + k0,  &As[buf][(256 + t) * 8]);
        gload16(Bp + k0,            &Bs[buf][t * 8]);
        gload16(Bp + 32 * Dn + k0,  &Bs[buf][(256 + t) * 8]);
        gload16(Bp + 64 * Dn + k0,  &Bs[buf][(512 + t) * 8]);
        gload16(Bp + 96 * Dn + k0,  &Bs[buf][(768 + t) * 8]);
    };

    stage(0, 0);
    for (int ki = 0; ki < 16; ++ki) {
        __syncthreads();
        if (ki + 1 < 16) stage((ki + 1) & 1, (ki + 1) * 64);
        const u16* as = As[ki & 1];
        const u16* bs = Bs[ki & 1];
#pragma unroll
        for (int kk = 0; kk < 2; ++kk) {
            const int so = ((kk * 4 + g) ^ (c & 7)) << 3;
            bf16x8 a[2], b[4];
#pragma unroll
            for (int mi = 0; mi < 2; ++mi)
                a[mi] = *(const bf16x8*)&as[(wr * 32 + mi * 16 + c) * 64 + so];
#pragma unroll
            for (int ni = 0; ni < 4; ++ni)
                b[ni] = *(const bf16x8*)&bs[(wc * 64 + ni * 16 + c) * 64 + so];
            __builtin_amdgcn_s_setprio(1);
#pragma unroll
            for (int mi = 0; mi < 2; ++mi)
#pragma unroll
                for (int ni = 0; ni < 4; ++ni)
                    acc[mi][ni] = __builtin_amdgcn_mfma_f32_16x16x32_bf16(
                        a[mi], b[ni], acc[mi][ni], 0, 0, 0);
            __builtin_amdgcn_s_setprio(0);
        }
    }

#pragma unroll
    for (int mi = 0; mi < 2; ++mi)
#pragma unroll
        for (int j = 0; j < 4; ++j) {
            size_t row = bm + wr * 32 + mi * 16 + g * 4 + j;
            float prt = 0.f;
#pragma unroll
            for (int ni = 0; ni < 4; ++ni) {
                int col = bn + wc * 64 + ni * 16 + c;
                float v = acc[mi][ni][j] + bias[col];
                C[row * Dn + col] = v;
                if (col != 0) prt += v * v;   // exclude the time slot
            }
            prt = red16_add(prt);             // 64-col partial for this row
            if (c == 0) atomicAdd(&ssq[row], prt);
        }
}

// ---------------------------------------------------------------------------
// Final fixup: out[row][0] = sqrt(1 + sum_{i>=1} out[row][i]^2).
// ---------------------------------------------------------------------------
__global__ __launch_bounds__(256)
void lorentz_fix(float* __restrict__ z, const float* __restrict__ ssq)
{
    int row = blockIdx.x * 256 + threadIdx.x;
    z[(size_t)row * Dn] = sqrtf(1.f + ssq[row]);
}

// ---------------------------------------------------------------------------
extern "C" void kernel_launch(void* const* d_in, const int* in_sizes, int n_in,
                              void* d_out, int out_size, void* d_ws, size_t ws_size,
                              hipStream_t stream)
{
    const float* query = (const float*)d_in[0];
    const float* key_  = (const float*)d_in[1];
    const float* value = (const float*)d_in[2];
    const float* W_Q   = (const float*)d_in[3];
    const float* b_Q   = (const float*)d_in[4];
    const float* W_K   = (const float*)d_in[5];
    const float* b_K   = (const float*)d_in[6];
    const float* W_V   = (const float*)d_in[7];
    const float* b_V   = (const float*)d_in[8];
    const float* W_O   = (const float*)d_in[9];
    const float* b_O   = (const float*)d_in[10];

    // ws layout (u16 elems; 64 MiB budget).  part aliases wq/wk/wv/v_ln,
    // all of which are dead before attn_mfma runs.  ssq lives at 60 MB.
    const size_t MD = (size_t)Mn * Dn;   // 4M elems (8 MiB)
    const size_t DD = (size_t)Dn * Dn;   // 1M elems (2 MiB)
    u16* xq   = (u16*)d_ws;              //  0M..4M   swz input q
    u16* xk   = xq + MD;                 //  4M..8M   swz input k
    u16* xv   = xk + MD;                 //  8M..12M  swz input v
    u16* wo   = xv + MD;                 // 12M..13M  W_O (swz + col perm)
    u16* q_t  = wo + DD;                 // 13M..17M  [b][h][l][64slots]
    u16* k_t  = q_t + MD;                // 17M..21M
    u16* wq   = k_t + MD;                // 21M..22M
    u16* wk   = wq + DD;                 // 22M..23M
    u16* wv   = wk + DD;                 // 23M..24M
    u16* v_ln = wv + DD;                 // 24M..28M  V projection
    u16* part = wq;                      // 21M..29.4M  bf16 partials (16 MiB)
    u16* v_T  = xv;                      // alias: xv dead after gemm_qkv
    u16* cat  = xk;                      // alias: xk dead after gemm_qkv
    float* ssq = (float*)((u16*)d_ws + (size_t)30 * 1024 * 1024);  // 60MB..60.016MB

    dim3 ca(Mn * Dn / 1024, 7);                // (4096, 7): 3 inputs + 4 weights
    cvt_all<<<ca, 256, 0, stream>>>(query, key_, value, W_Q, W_K, W_V, W_O,
                                    xq, xk, xv, wq, wk, wv, wo, ssq);

    gemm_qkv<<<1536, 256, 0, stream>>>(xq, xk, xv, wq, wk, wv,
                                       b_Q, b_K, b_V, q_t, k_t, v_ln);

    dim3 tg(32, Ln / 64);                      // (32, 32)
    transpose_v<<<tg, 256, 0, stream>>>(v_ln, v_T);

    attn_mfma<<<1024, 256, 0, stream>>>(q_t, k_t, v_T, part);  // XCD-swizzled 1D

    attn_combine<<<4096, 256, 0, stream>>>(part, cat);

    gemm_o<<<512, 256, 0, stream>>>(cat, wo, b_O, (float*)d_out, ssq);
    lorentz_fix<<<Mn / 256, 256, 0, stream>>>((float*)d_out, ssq);
}